// Round 11
// baseline (379.480 us; speedup 1.0000x reference)
//
#include <hip/hip_runtime.h>
#include <hip/hip_bf16.h>

// Transformer block forward: B=2, T=2048, E=1024, H=16, D=64.
// Pipeline: transpose weights->bf16 | LN1 | QKV GEMM (256^2 8-wave pipelined) |
//           V transpose | flash attn v6 | out-proj+res (128^2) | LN2 |
//           FC+GELU (256^2) | proj+res (128^2).

#define T_DIM 2048
#define E_DIM 1024
#define NH 16

using short8 = __attribute__((__ext_vector_type__(8))) short;
using f32x4  = __attribute__((__ext_vector_type__(4))) float;

static __device__ __forceinline__ f32x4 zero4() {
  f32x4 z = {0.f, 0.f, 0.f, 0.f};
  return z;
}

static __device__ __forceinline__ unsigned short f2bfbits(float f) {
  __hip_bfloat16 h = __float2bfloat16(f);
  return *reinterpret_cast<unsigned short*>(&h);
}

static __device__ __forceinline__ float gelu_tanh(float x) {
  float z = 0.7978845608028654f * (x + 0.044715f * x * x * x);
  float e = __expf(2.0f * z);
  float th = 1.0f - 2.0f / (e + 1.0f);
  return 0.5f * x * (1.0f + th);
}

// ---------------- transpose f32 [K][N] -> bf16 [N][K] ----------------
__global__ __launch_bounds__(256) void transpose_f32_to_bf16(
    const float* __restrict__ in, __hip_bfloat16* __restrict__ out, int K, int N) {
  __shared__ float tl[64][65];
  const int n0 = blockIdx.x * 64, k0 = blockIdx.y * 64;
  const int t = threadIdx.x;
  const int rr = t >> 4;        // 0..15
  const int cc = (t & 15) * 4;  // 0..60
#pragma unroll
  for (int i = 0; i < 4; ++i) {
    const int row = rr + i * 16;
    const float4 v = *reinterpret_cast<const float4*>(&in[(size_t)(k0 + row) * N + n0 + cc]);
    tl[row][cc] = v.x; tl[row][cc + 1] = v.y; tl[row][cc + 2] = v.z; tl[row][cc + 3] = v.w;
  }
  __syncthreads();
#pragma unroll
  for (int i = 0; i < 4; ++i) {
    const int row = rr + i * 16;  // output row (n)
    ushort4 pk;
    pk.x = f2bfbits(tl[cc + 0][row]);
    pk.y = f2bfbits(tl[cc + 1][row]);
    pk.z = f2bfbits(tl[cc + 2][row]);
    pk.w = f2bfbits(tl[cc + 3][row]);
    *reinterpret_cast<ushort4*>(&out[(size_t)(n0 + row) * K + k0 + cc]) = pk;
  }
}

// ---------------- LayerNorm rows of 1024, f32 in -> bf16 out ----------------
__global__ __launch_bounds__(256) void layernorm_bf16(
    const float* __restrict__ x, const float* __restrict__ g, const float* __restrict__ bb,
    __hip_bfloat16* __restrict__ out) {
  const int lane = threadIdx.x & 63;
  const int row = blockIdx.x * 4 + (threadIdx.x >> 6);
  const float* xr = x + (size_t)row * E_DIM;
  float4 v[4];
  float s = 0.f, s2 = 0.f;
#pragma unroll
  for (int i = 0; i < 4; ++i) {
    v[i] = *reinterpret_cast<const float4*>(&xr[(i * 64 + lane) * 4]);
    s  += v[i].x + v[i].y + v[i].z + v[i].w;
    s2 += v[i].x * v[i].x + v[i].y * v[i].y + v[i].z * v[i].z + v[i].w * v[i].w;
  }
#pragma unroll
  for (int m = 1; m < 64; m <<= 1) { s += __shfl_xor(s, m); s2 += __shfl_xor(s2, m); }
  const float mu = s * (1.0f / E_DIM);
  const float var = s2 * (1.0f / E_DIM) - mu * mu;
  const float rstd = rsqrtf(var + 1e-5f);
  __hip_bfloat16* orow = out + (size_t)row * E_DIM;
#pragma unroll
  for (int i = 0; i < 4; ++i) {
    const int col = (i * 64 + lane) * 4;
    const float4 gv = *reinterpret_cast<const float4*>(&g[col]);
    const float4 bv = *reinterpret_cast<const float4*>(&bb[col]);
    ushort4 pk;
    pk.x = f2bfbits((v[i].x - mu) * rstd * gv.x + bv.x);
    pk.y = f2bfbits((v[i].y - mu) * rstd * gv.y + bv.y);
    pk.z = f2bfbits((v[i].z - mu) * rstd * gv.z + bv.z);
    pk.w = f2bfbits((v[i].w - mu) * rstd * gv.w + bv.w);
    *reinterpret_cast<ushort4*>(&orow[col]) = pk;
  }
}

// ---------------- 128^2 bf16 GEMM (kept for N=1024 outputs) ----------------
template <int GELU_ACT, int ADD_RES, int OUT_F32, int SCALE_Q>
__global__ __launch_bounds__(256, 2) void gemm_bt(
    const __hip_bfloat16* __restrict__ A, const __hip_bfloat16* __restrict__ Bt,
    const float* __restrict__ bias, const float* __restrict__ res,
    float* __restrict__ outF, __hip_bfloat16* __restrict__ outB,
    int M, int N, int K) {
  __shared__ __hip_bfloat16 sA[2][128 * 32];
  __shared__ __hip_bfloat16 sB[2][128 * 32];
  const int tid = threadIdx.x;
  const int w = tid >> 6, l = tid & 63;
  const int lhi = l >> 4, llo = l & 15;
  const int gx = gridDim.x;
  int wg = blockIdx.y * gx + blockIdx.x;
  const int cpx = (gx * gridDim.y) >> 3;
  wg = (wg & 7) * cpx + (wg >> 3);
  const int m0 = (wg / gx) * 128, n0 = (wg % gx) * 128;
  const int wr = (w >> 1) * 64, wc = (w & 1) * 64;
  f32x4 acc[4][4];
#pragma unroll
  for (int i = 0; i < 4; ++i)
#pragma unroll
    for (int j = 0; j < 4; ++j) acc[i][j] = zero4();

  const int nt = K >> 5;
  auto stage = [&](int buf, int t) {
    const int k0 = t << 5;
#pragma unroll
    for (int i = 0; i < 2; ++i) {
      const int r = i * 64 + (tid >> 2);
      const int c = (tid & 3) * 8;
      const int e = i * 2048 + tid * 8;
      __builtin_amdgcn_global_load_lds(
          (const __attribute__((address_space(1))) void*)(A + (size_t)(m0 + r) * K + k0 + c),
          (__attribute__((address_space(3))) void*)(&sA[buf][e]), 16, 0, 0);
      __builtin_amdgcn_global_load_lds(
          (const __attribute__((address_space(1))) void*)(Bt + (size_t)(n0 + r) * K + k0 + c),
          (__attribute__((address_space(3))) void*)(&sB[buf][e]), 16, 0, 0);
    }
  };

  stage(0, 0);
  for (int t = 0; t < nt; ++t) {
    const int cur = t & 1;
    __syncthreads();
    if (t + 1 < nt) stage(cur ^ 1, t + 1);
    const __hip_bfloat16* pa = sA[cur];
    const __hip_bfloat16* pb = sB[cur];
    short8 af[4], bfr[4];
#pragma unroll
    for (int i = 0; i < 4; ++i) {
      af[i]  = *reinterpret_cast<const short8*>(pa + (wr + i * 16 + llo) * 32 + lhi * 8);
      bfr[i] = *reinterpret_cast<const short8*>(pb + (wc + i * 16 + llo) * 32 + lhi * 8);
    }
#pragma unroll
    for (int mi = 0; mi < 4; ++mi)
#pragma unroll
      for (int ni = 0; ni < 4; ++ni)
        acc[mi][ni] = __builtin_amdgcn_mfma_f32_16x16x32_bf16(af[mi], bfr[ni], acc[mi][ni], 0, 0, 0);
  }

#pragma unroll
  for (int mi = 0; mi < 4; ++mi) {
#pragma unroll
    for (int ni = 0; ni < 4; ++ni) {
      const int row = m0 + wr + mi * 16 + lhi * 4;
      const int col = n0 + wc + ni * 16 + llo;
      const float bc = bias[col];
      float qs = 1.0f;
      if (SCALE_Q) qs = ((col % 192) < 64) ? 0.125f : 1.0f;
#pragma unroll
      for (int j = 0; j < 4; ++j) {
        float v = acc[mi][ni][j] + bc;
        if (SCALE_Q) v *= qs;
        if (GELU_ACT) v = gelu_tanh(v);
        if (ADD_RES) v += res[(size_t)(row + j) * N + col];
        if (OUT_F32) outF[(size_t)(row + j) * N + col] = v;
        else outB[(size_t)(row + j) * N + col] = __float2bfloat16(v);
      }
    }
  }
}

// ---------------- 256^2 8-wave pipelined bf16 GEMM (T3+T4+T5, linear LDS) ----
// BM=BN=256, BK=64, 512 thr = 8 waves (2M x 4N), per-wave C = 128x64.
// Double-buffered LDS (128 KiB). Staging = 8 units/tile (1 global_load_lds per
// thread each); 2 issued before the boundary wait -> counted vmcnt(2) keeps
// loads in flight across barriers (never drain to 0 in steady state); 6 units
// spread across the 4 MFMA phases. Raw s_barrier + asm-"memory" waits.
template <int GELU_ACT, int SCALE_Q>
__global__ __launch_bounds__(512, 2) void gemm256(
    const __hip_bfloat16* __restrict__ A, const __hip_bfloat16* __restrict__ Bt,
    const float* __restrict__ bias, __hip_bfloat16* __restrict__ outB,
    int M, int N, int K) {
  __shared__ __align__(16) __hip_bfloat16 sA[2][256 * 64];
  __shared__ __align__(16) __hip_bfloat16 sB[2][256 * 64];
  const int tid = threadIdx.x;
  const int w = tid >> 6, l = tid & 63;
  const int lhi = l >> 4, llo = l & 15;
  const int gx = gridDim.x;
  int wg = blockIdx.y * gx + blockIdx.x;
  const int cpx = (gx * gridDim.y) >> 3;
  wg = (wg & 7) * cpx + (wg >> 3);
  const int m0 = (wg / gx) * 256, n0 = (wg % gx) * 256;
  const int wr = (w >> 2) * 128;  // 2 M-halves
  const int wc = (w & 3) * 64;    // 4 N-quarters
  f32x4 acc[8][4];
#pragma unroll
  for (int i = 0; i < 8; ++i)
#pragma unroll
    for (int j = 0; j < 4; ++j) acc[i][j] = zero4();

  const int nt = K >> 6;
  // stage unit u: op = u>>2 (0=A,1=B), 64-row chunk = u&3; 1 load per thread.
  auto stageU = [&](int buf, int t, int u) {
    const int k0 = t << 6;
    const int r = ((u & 3) << 6) + (tid >> 3);
    const int c = (tid & 7) << 3;
    const int e = ((u & 3) << 12) + (tid << 3);
    if (u < 4)
      __builtin_amdgcn_global_load_lds(
          (const __attribute__((address_space(1))) void*)(A + (size_t)(m0 + r) * K + k0 + c),
          (__attribute__((address_space(3))) void*)(&sA[buf][e]), 16, 0, 0);
    else
      __builtin_amdgcn_global_load_lds(
          (const __attribute__((address_space(1))) void*)(Bt + (size_t)(n0 + r) * K + k0 + c),
          (__attribute__((address_space(3))) void*)(&sB[buf][e]), 16, 0, 0);
  };

#pragma unroll
  for (int u = 0; u < 8; ++u) stageU(0, 0, u);  // prologue: tile 0

  for (int t = 0; t < nt; ++t) {
    const int b = t & 1;
    __builtin_amdgcn_s_barrier();  // all waves done reading buf b^1 (tile t-1)
    if (t + 1 < nt) {
      stageU(b ^ 1, t + 1, 0);
      stageU(b ^ 1, t + 1, 1);
      asm volatile("s_waitcnt vmcnt(2)" ::: "memory");  // tile t landed; 2 in flight
    } else {
      asm volatile("s_waitcnt vmcnt(0)" ::: "memory");
    }
    __builtin_amdgcn_s_barrier();  // cross-wave: tile t LDS valid
    const __hip_bfloat16* pa = sA[b];
    const __hip_bfloat16* pb = sB[b];
#pragma unroll
    for (int q = 0; q < 4; ++q) {
      const int mh = q >> 1, nh = q & 1;
      short8 af[4][2], bq[2][2];
#pragma unroll
      for (int i = 0; i < 4; ++i)
#pragma unroll
        for (int kk = 0; kk < 2; ++kk)
          af[i][kk] = *reinterpret_cast<const short8*>(
              pa + (wr + (mh * 4 + i) * 16 + llo) * 64 + kk * 32 + lhi * 8);
#pragma unroll
      for (int n = 0; n < 2; ++n)
#pragma unroll
        for (int kk = 0; kk < 2; ++kk)
          bq[n][kk] = *reinterpret_cast<const short8*>(
              pb + (wc + (nh * 2 + n) * 16 + llo) * 64 + kk * 32 + lhi * 8);
      if (t + 1 < nt && q < 3) {  // 6 remaining units under the MFMA phases
        stageU(b ^ 1, t + 1, 2 + q * 2);
        stageU(b ^ 1, t + 1, 3 + q * 2);
      }
      __builtin_amdgcn_s_setprio(1);
#pragma unroll
      for (int i = 0; i < 4; ++i)
#pragma unroll
        for (int n = 0; n < 2; ++n)
#pragma unroll
          for (int kk = 0; kk < 2; ++kk)
            acc[mh * 4 + i][nh * 2 + n] = __builtin_amdgcn_mfma_f32_16x16x32_bf16(
                af[i][kk], bq[n][kk], acc[mh * 4 + i][nh * 2 + n], 0, 0, 0);
      __builtin_amdgcn_s_setprio(0);
      if (q < 3) __builtin_amdgcn_s_barrier();  // phase lock (loop-top barrier covers q=3)
    }
  }

#pragma unroll
  for (int mi = 0; mi < 8; ++mi) {
#pragma unroll
    for (int ni = 0; ni < 4; ++ni) {
      const int row = m0 + wr + mi * 16 + lhi * 4;
      const int col = n0 + wc + ni * 16 + llo;
      const float bc = bias[col];
      float qs = 1.0f;
      if (SCALE_Q) qs = ((col % 192) < 64) ? 0.125f : 1.0f;
#pragma unroll
      for (int j = 0; j < 4; ++j) {
        float v = acc[mi][ni][j] + bc;
        if (SCALE_Q) v *= qs;
        if (GELU_ACT) v = gelu_tanh(v);
        outB[(size_t)(row + j) * N + col] = __float2bfloat16(v);
      }
    }
  }
}

// ---------------- V transpose: qkv V-region -> vt[b][h][d][T] ----------------
__global__ __launch_bounds__(256) void transpose_v(
    const __hip_bfloat16* __restrict__ qkv, __hip_bfloat16* __restrict__ vt) {
  const int t0 = blockIdx.x * 64, h = blockIdx.y, b = blockIdx.z;
  const size_t rb = (size_t)b * T_DIM;
  const size_t obase = ((size_t)(b * NH + h) * 64) * T_DIM;
  __shared__ unsigned short tl[64][64];
  const int tid = threadIdx.x;
#pragma unroll
  for (int k = 0; k < 2; ++k) {
    const int e = k * 2048 + tid * 8;
    const int tr = e >> 6, dc = e & 63;
    const short8 v =
        *reinterpret_cast<const short8*>(qkv + (rb + t0 + tr) * 3072 + h * 192 + 128 + dc);
    *reinterpret_cast<short8*>(&tl[tr][dc ^ ((tr & 7) << 3)]) = v;
  }
  __syncthreads();
#pragma unroll
  for (int k = 0; k < 2; ++k) {
    const int e = k * 2048 + tid * 8;
    const int dr = e >> 6, tc = e & 63;
    short8 o;
#pragma unroll
    for (int jj = 0; jj < 8; ++jj)
      o[jj] = (short)tl[tc + jj][dr ^ (((tc + jj) & 7) << 3)];
    *reinterpret_cast<short8*>(&vt[obase + (size_t)dr * T_DIM + t0 + tc]) = o;
  }
}

// ---------------- causal flash attention v6 (unchanged from round 10) --------
__global__ __launch_bounds__(256) void attn_fwd(
    const __hip_bfloat16* __restrict__ qkv, const __hip_bfloat16* __restrict__ vt,
    __hip_bfloat16* __restrict__ aout) {
  const int hb = blockIdx.x;
  const int h = hb & 15, b = hb >> 4;
  const int tid = threadIdx.x, w = tid >> 6, l = tid & 63;
  const int lhi = l >> 4, llo = l & 15;
  const int pr = w >> 1;               // pair slot in block (0,1)
  const int s = w & 1;                 // kv half
  const int p = blockIdx.y * 2 + pr;   // pair index 0..31
  const size_t rb = (size_t)b * T_DIM;
  const size_t vbase = ((size_t)(b * NH + h) * 64) * T_DIM;
  __shared__ __hip_bfloat16 sP[4][32][72];
  __shared__ float mrg[2][64][49];  // [pair][lane][32 O + 8 m + 8 l + pad]

  short8 onesb;
#pragma unroll
  for (int i = 0; i < 8; ++i) onesb[i] = (short)0x3F80;  // bf16 1.0

#pragma unroll
  for (int half = 0; half < 2; ++half) {
    const int tile = half ? (63 - p) : p;  // 32-row q tile, 0..63
    const int q0 = tile * 32;
    const int nkv = (tile >> 1) + 1;       // kv-tiles of 64
    const int base = (tile & 1) << 5;      // diag offset: 0 or 32
    const int kt_begin = s ? (nkv >> 1) : 0;
    const int kt_end   = s ? nkv : (nkv >> 1);

    short8 qf[2][2];
#pragma unroll
    for (int mf = 0; mf < 2; ++mf) {
      const __hip_bfloat16* qp =
          qkv + ((rb + q0 + mf * 16 + llo) * 3072 + h * 192 + lhi * 8);
      qf[mf][0] = *reinterpret_cast<const short8*>(qp);
      qf[mf][1] = *reinterpret_cast<const short8*>(qp + 32);
    }
    float mrun[2][4], lrun[2][4];
    f32x4 oacc[2][4];
#pragma unroll
    for (int mf = 0; mf < 2; ++mf)
#pragma unroll
      for (int j = 0; j < 4; ++j) { mrun[mf][j] = -1e30f; lrun[mf][j] = 0.f; }
#pragma unroll
    for (int mf = 0; mf < 2; ++mf)
#pragma unroll
      for (int di = 0; di < 4; ++di) oacc[mf][di] = zero4();

    auto loadK = [&](short8 (&dst)[4][2], int k0) {
#pragma unroll
      for (int ni = 0; ni < 4; ++ni) {
        const __hip_bfloat16* kp =
            qkv + ((rb + k0 + ni * 16 + llo) * 3072 + h * 192 + 64 + lhi * 8);
        dst[ni][0] = *reinterpret_cast<const short8*>(kp);
        dst[ni][1] = *reinterpret_cast<const short8*>(kp + 32);
      }
    };

    auto step = [&](short8 (&cK)[4][2], short8 (&nK)[4][2], int kt) {
      const bool diag = (kt == nkv - 1);
      const bool evendiag = diag && (base == 0);  // ni>=2 / k>=32 dead
      // S = Q K^T
      f32x4 sc[2][4];
      __builtin_amdgcn_s_setprio(1);
#pragma unroll
      for (int mf = 0; mf < 2; ++mf)
#pragma unroll
        for (int ni = 0; ni < 4; ++ni) {
          sc[mf][ni] = zero4();
          if (!evendiag || ni < 2) {
            sc[mf][ni] =
                __builtin_amdgcn_mfma_f32_16x16x32_bf16(qf[mf][0], cK[ni][0], sc[mf][ni], 0, 0, 0);
            sc[mf][ni] =
                __builtin_amdgcn_mfma_f32_16x16x32_bf16(qf[mf][1], cK[ni][1], sc[mf][ni], 0, 0, 0);
          }
        }
      __builtin_amdgcn_s_setprio(0);
      // prefetch next K tile
      if (kt + 1 < kt_end) loadK(nK, (kt + 1) * 64);
      // V for THIS step (L2 latency hides under softmax)
      short8 vCur[4][2];
#pragma unroll
      for (int di = 0; di < 4; ++di) {
        const __hip_bfloat16* vp =
            vt + (vbase + (size_t)(di * 16 + llo) * T_DIM + kt * 64 + lhi * 8);
        vCur[di][0] = *reinterpret_cast<const short8*>(vp);
        vCur[di][1] = *reinterpret_cast<const short8*>(vp + 32);
      }
      // online softmax
      float corr[2][4];
#pragma unroll
      for (int mf = 0; mf < 2; ++mf)
#pragma unroll
        for (int j = 0; j < 4; ++j) {
          const int ql = mf * 16 + lhi * 4 + j;
          float sv[4];
#pragma unroll
          for (int ni = 0; ni < 4; ++ni) {
            float sval = sc[mf][ni][j];
            if (diag) sval = (ni * 16 + llo <= base + ql) ? sval : -1e30f;
            sv[ni] = sval;
          }
          float mx = fmaxf(fmaxf(sv[0], sv[1]), fmaxf(sv[2], sv[3]));
#pragma unroll
          for (int d = 1; d < 16; d <<= 1) mx = fmaxf(mx, __shfl_xor(mx, d));
          const float mnew = fmaxf(mrun[mf][j], mx);
          const float c = __expf(mrun[mf][j] - mnew);
          mrun[mf][j] = mnew;
          corr[mf][j] = c;
#pragma unroll
          for (int ni = 0; ni < 4; ++ni)
            sP[w][mf * 16 + lhi * 4 + j][ni * 16 + llo] = __float2bfloat16(__expf(sv[ni] - mnew));
#pragma unroll
          for (int di = 0; di < 4; ++di) oacc[mf][di][j] *= c;
        }
      asm volatile("s_waitcnt lgkmcnt(0)" ::: "memory");
      // O += P V ; l += P 1
      __builtin_amdgcn_s_setprio(1);
#pragma unroll
      for (int mf = 0; mf < 2; ++mf) {
        const short8 pf0 = *reinterpret_cast<const short8*>(&sP[w][mf * 16 + llo][lhi * 8]);
        const short8 pf1 = *reinterpret_cast<const short8*>(&sP[w][mf * 16 + llo][32 + lhi * 8]);
        f32x4 lacc = zero4();
        lacc = __builtin_amdgcn_mfma_f32_16x16x32_bf16(pf0, onesb, lacc, 0, 0, 0);
        if (!evendiag)
          lacc = __builtin_amdgcn_mfma_f32_16x16x32_bf16(pf1, onesb, lacc, 0, 0, 0);
#pragma unroll
        for (int di = 0; di < 4; ++di) {
          oacc[mf][di] =
              __builtin_amdgcn_mfma_f32_16x16x32_bf16(pf0, vCur[di][0], oacc[mf][di], 0, 0, 0);
          if (!evendiag)
            oacc[mf][di] =
                __builtin_amdgcn_mfma_f32_16x16x32_bf16(pf1, vCur[di][1], oacc[mf][di], 0, 0, 0);
        }
#pragma unroll
        for (int j = 0; j < 4; ++j)
          lrun[mf][j] = lrun[mf][j] * corr[mf][j] + lacc[j];
      }
      __builtin_amdgcn_s_setprio(0);
    };

    short8 kA[4][2], kB[4][2];
    if (kt_begin < kt_end) loadK(kA, kt_begin * 64);
    for (int kt = kt_begin; kt < kt_end; ++kt) {
      if ((kt - kt_begin) & 1) step(kB, kA, kt);
      else                     step(kA, kB, kt);
    }

    // ---- merge the two kv-halves (flash-decoding combine) ----
    if (s == 0) {
      float* dst = &mrg[pr][l][0];
#pragma unroll
      for (int mf = 0; mf < 2; ++mf)
#pragma unroll
        for (int di = 0; di < 4; ++di)
#pragma unroll
          for (int j = 0; j < 4; ++j) dst[(mf * 4 + di) * 4 + j] = oacc[mf][di][j];
#pragma unroll
      for (int mf = 0; mf < 2; ++mf)
#pragma unroll
        for (int j = 0; j < 4; ++j) {
          dst[32 + mf * 4 + j] = mrun[mf][j];
          dst[40 + mf * 4 + j] = lrun[mf][j];
        }
    }
    __syncthreads();
    if (s == 1) {
      const float* src = &mrg[pr][l][0];
#pragma unroll
      for (int mf = 0; mf < 2; ++mf)
#pragma unroll
        for (int j = 0; j < 4; ++j) {
          const float m0 = src[32 + mf * 4 + j], l0 = src[40 + mf * 4 + j];
          const float m1 = mrun[mf][j], l1 = lrun[mf][j];
          const float mm = fmaxf(m0, m1);
          const float a0 = __expf(m0 - mm), a1 = __expf(m1 - mm);
          const float linv = 1.0f / (l0 * a0 + l1 * a1);
          const size_t row = rb + q0 + mf * 16 + lhi * 4 + j;
#pragma unroll
          for (int di = 0; di < 4; ++di) {
            const float o = (src[(mf * 4 + di) * 4 + j] * a0 + oacc[mf][di][j] * a1) * linv;
            aout[row * 1024 + h * 64 + di * 16 + llo] = __float2bfloat16(o);
          }
        }
    }
    __syncthreads();
  }
}

// ---------------- launch ----------------
extern "C" void kernel_launch(void* const* d_in, const int* in_sizes, int n_in,
                              void* d_out, int out_size, void* d_ws, size_t ws_size,
                              hipStream_t stream) {
  (void)in_sizes; (void)n_in; (void)out_size; (void)ws_size;
  const float* x      = (const float*)d_in[0];
  const float* ln1_g  = (const float*)d_in[1];
  const float* ln1_b  = (const float*)d_in[2];
  const float* w_qkv  = (const float*)d_in[3];
  const float* b_qkv  = (const float*)d_in[4];
  const float* w_out  = (const float*)d_in[5];
  const float* b_out  = (const float*)d_in[6];
  const float* ln2_g  = (const float*)d_in[7];
  const float* ln2_b  = (const float*)d_in[8];
  const float* w_fc   = (const float*)d_in[9];
  const float* b_fc   = (const float*)d_in[10];
  const float* w_proj = (const float*)d_in[11];
  const float* b_proj = (const float*)d_in[12];
  float* out = (float*)d_out;

  const int M = 2 * T_DIM;  // 4096 rows
  char* wsp = (char*)d_ws;
  size_t off = 0;
  auto carve = [&](size_t bytes) {
    void* p = wsp + off;
    off += (bytes + 255) & ~(size_t)255;
    return p;
  };
  __hip_bfloat16* wt_qkv  = (__hip_bfloat16*)carve((size_t)3072 * 1024 * 2);
  __hip_bfloat16* wt_out  = (__hip_bfloat16*)carve((size_t)1024 * 1024 * 2);
  __hip_bfloat16* wt_fc   = (__hip_bfloat16*)carve((size_t)4096 * 1024 * 2);
  __hip_bfloat16* wt_proj = (__hip_bfloat16*)carve((size_t)1024 * 4096 * 2);
  __hip_bfloat16* ln1o    = (__hip_bfloat16*)carve((size_t)M * 1024 * 2);
  __hip_bfloat16* qkvb    = (__hip_bfloat16*)carve((size_t)M * 3072 * 2);
  __hip_bfloat16* vtb     = (__hip_bfloat16*)carve((size_t)2 * NH * 64 * T_DIM * 2);
  __hip_bfloat16* attnb   = (__hip_bfloat16*)carve((size_t)M * 1024 * 2);
  float*          x2      = (float*)carve((size_t)M * 1024 * 4);
  __hip_bfloat16* h1      = (__hip_bfloat16*)carve((size_t)M * 4096 * 2);
  __hip_bfloat16* ln2o    = ln1o;  // ln1 output dead after QKV GEMM; reuse

  // weights -> bf16 [N][K]
  transpose_f32_to_bf16<<<dim3(3072 / 64, 1024 / 64), 256, 0, stream>>>(w_qkv, wt_qkv, 1024, 3072);
  transpose_f32_to_bf16<<<dim3(1024 / 64, 1024 / 64), 256, 0, stream>>>(w_out, wt_out, 1024, 1024);
  transpose_f32_to_bf16<<<dim3(4096 / 64, 1024 / 64), 256, 0, stream>>>(w_fc, wt_fc, 1024, 4096);
  transpose_f32_to_bf16<<<dim3(1024 / 64, 4096 / 64), 256, 0, stream>>>(w_proj, wt_proj, 4096, 1024);

  layernorm_bf16<<<M / 4, 256, 0, stream>>>(x, ln1_g, ln1_b, ln1o);
  gemm256<0, 1><<<dim3(3072 / 256, M / 256), 512, 0, stream>>>(
      ln1o, wt_qkv, b_qkv, qkvb, M, 3072, 1024);
  transpose_v<<<dim3(T_DIM / 64, NH, 2), 256, 0, stream>>>(qkvb, vtb);
  attn_fwd<<<dim3(32, 16), 256, 0, stream>>>(qkvb, vtb, attnb);
  gemm_bt<0, 1, 1, 0><<<dim3(1024 / 128, M / 128), 256, 0, stream>>>(
      attnb, wt_out, b_out, x, x2, nullptr, M, 1024, 1024);
  layernorm_bf16<<<M / 4, 256, 0, stream>>>(x2, ln2_g, ln2_b, ln2o);
  gemm256<1, 0><<<dim3(4096 / 256, M / 256), 512, 0, stream>>>(
      ln2o, wt_fc, b_fc, h1, M, 4096, 1024);
  gemm_bt<0, 1, 1, 0><<<dim3(1024 / 128, M / 128), 256, 0, stream>>>(
      h1, wt_proj, b_proj, x2, out, nullptr, M, 1024, 4096);
}

// Round 13
// 328.314 us; speedup vs baseline: 1.1558x; 1.1558x over previous
//
#include <hip/hip_runtime.h>
#include <hip/hip_bf16.h>

// Transformer block forward: B=2, T=2048, E=1024, H=16, D=64.
// Pipeline: transpose weights->bf16 | LN1 | QKV GEMM (256^2 8-wave pipelined,
//           T2-swizzled LDS) | V transpose | flash attn v6 |
//           out-proj+res (128^2 swz) | LN2 | FC+GELU (256^2) | proj+res (128^2).

#define T_DIM 2048
#define E_DIM 1024
#define NH 16

using short8 = __attribute__((__ext_vector_type__(8))) short;
using f32x4  = __attribute__((__ext_vector_type__(4))) float;

static __device__ __forceinline__ f32x4 zero4() {
  f32x4 z = {0.f, 0.f, 0.f, 0.f};
  return z;
}

static __device__ __forceinline__ unsigned short f2bfbits(float f) {
  __hip_bfloat16 h = __float2bfloat16(f);
  return *reinterpret_cast<unsigned short*>(&h);
}

static __device__ __forceinline__ float gelu_tanh(float x) {
  float z = 0.7978845608028654f * (x + 0.044715f * x * x * x);
  float e = __expf(2.0f * z);
  float th = 1.0f - 2.0f / (e + 1.0f);
  return 0.5f * x * (1.0f + th);
}

// ---------------- transpose f32 [K][N] -> bf16 [N][K] ----------------
__global__ __launch_bounds__(256) void transpose_f32_to_bf16(
    const float* __restrict__ in, __hip_bfloat16* __restrict__ out, int K, int N) {
  __shared__ float tl[64][65];
  const int n0 = blockIdx.x * 64, k0 = blockIdx.y * 64;
  const int t = threadIdx.x;
  const int rr = t >> 4;        // 0..15
  const int cc = (t & 15) * 4;  // 0..60
#pragma unroll
  for (int i = 0; i < 4; ++i) {
    const int row = rr + i * 16;
    const float4 v = *reinterpret_cast<const float4*>(&in[(size_t)(k0 + row) * N + n0 + cc]);
    tl[row][cc] = v.x; tl[row][cc + 1] = v.y; tl[row][cc + 2] = v.z; tl[row][cc + 3] = v.w;
  }
  __syncthreads();
#pragma unroll
  for (int i = 0; i < 4; ++i) {
    const int row = rr + i * 16;  // output row (n)
    ushort4 pk;
    pk.x = f2bfbits(tl[cc + 0][row]);
    pk.y = f2bfbits(tl[cc + 1][row]);
    pk.z = f2bfbits(tl[cc + 2][row]);
    pk.w = f2bfbits(tl[cc + 3][row]);
    *reinterpret_cast<ushort4*>(&out[(size_t)(n0 + row) * K + k0 + cc]) = pk;
  }
}

// ---------------- LayerNorm rows of 1024, f32 in -> bf16 out ----------------
__global__ __launch_bounds__(256) void layernorm_bf16(
    const float* __restrict__ x, const float* __restrict__ g, const float* __restrict__ bb,
    __hip_bfloat16* __restrict__ out) {
  const int lane = threadIdx.x & 63;
  const int row = blockIdx.x * 4 + (threadIdx.x >> 6);
  const float* xr = x + (size_t)row * E_DIM;
  float4 v[4];
  float s = 0.f, s2 = 0.f;
#pragma unroll
  for (int i = 0; i < 4; ++i) {
    v[i] = *reinterpret_cast<const float4*>(&xr[(i * 64 + lane) * 4]);
    s  += v[i].x + v[i].y + v[i].z + v[i].w;
    s2 += v[i].x * v[i].x + v[i].y * v[i].y + v[i].z * v[i].z + v[i].w * v[i].w;
  }
#pragma unroll
  for (int m = 1; m < 64; m <<= 1) { s += __shfl_xor(s, m); s2 += __shfl_xor(s2, m); }
  const float mu = s * (1.0f / E_DIM);
  const float var = s2 * (1.0f / E_DIM) - mu * mu;
  const float rstd = rsqrtf(var + 1e-5f);
  __hip_bfloat16* orow = out + (size_t)row * E_DIM;
#pragma unroll
  for (int i = 0; i < 4; ++i) {
    const int col = (i * 64 + lane) * 4;
    const float4 gv = *reinterpret_cast<const float4*>(&g[col]);
    const float4 bv = *reinterpret_cast<const float4*>(&bb[col]);
    ushort4 pk;
    pk.x = f2bfbits((v[i].x - mu) * rstd * gv.x + bv.x);
    pk.y = f2bfbits((v[i].y - mu) * rstd * gv.y + bv.y);
    pk.z = f2bfbits((v[i].z - mu) * rstd * gv.z + bv.z);
    pk.w = f2bfbits((v[i].w - mu) * rstd * gv.w + bv.w);
    *reinterpret_cast<ushort4*>(&orow[col]) = pk;
  }
}

// ---------------- 128^2 bf16 GEMM, T2-swizzled LDS ----------------
// LDS rows of 32 bf16 = 64B = 4 granules of 16B. Slot s = g ^ (r&3).
// global_load_lds writes linearly -> pre-permute the per-lane SOURCE granule;
// reads XOR the granule index with (row&3). 8-way -> 2-way bank conflicts.
template <int GELU_ACT, int ADD_RES, int OUT_F32, int SCALE_Q>
__global__ __launch_bounds__(256, 2) void gemm_bt(
    const __hip_bfloat16* __restrict__ A, const __hip_bfloat16* __restrict__ Bt,
    const float* __restrict__ bias, const float* __restrict__ res,
    float* __restrict__ outF, __hip_bfloat16* __restrict__ outB,
    int M, int N, int K) {
  __shared__ __hip_bfloat16 sA[2][128 * 32];
  __shared__ __hip_bfloat16 sB[2][128 * 32];
  const int tid = threadIdx.x;
  const int w = tid >> 6, l = tid & 63;
  const int lhi = l >> 4, llo = l & 15;
  const int gx = gridDim.x;
  int wg = blockIdx.y * gx + blockIdx.x;
  const int cpx = (gx * gridDim.y) >> 3;
  wg = (wg & 7) * cpx + (wg >> 3);
  const int m0 = (wg / gx) * 128, n0 = (wg % gx) * 128;
  const int wr = (w >> 1) * 64, wc = (w & 1) * 64;
  f32x4 acc[4][4];
#pragma unroll
  for (int i = 0; i < 4; ++i)
#pragma unroll
    for (int j = 0; j < 4; ++j) acc[i][j] = zero4();

  const int nt = K >> 5;
  // swizzled source granule: lane writes LDS slot (r=tid>>2, s=tid&3) linearly;
  // it must carry data granule s ^ (r&3).
  const int cswz = (((tid & 3) ^ ((tid >> 2) & 3)) << 3);
  auto stage = [&](int buf, int t) {
    const int k0 = t << 5;
#pragma unroll
    for (int i = 0; i < 2; ++i) {
      const int r = i * 64 + (tid >> 2);
      const int e = i * 2048 + tid * 8;
      __builtin_amdgcn_global_load_lds(
          (const __attribute__((address_space(1))) void*)(A + (size_t)(m0 + r) * K + k0 + cswz),
          (__attribute__((address_space(3))) void*)(&sA[buf][e]), 16, 0, 0);
      __builtin_amdgcn_global_load_lds(
          (const __attribute__((address_space(1))) void*)(Bt + (size_t)(n0 + r) * K + k0 + cswz),
          (__attribute__((address_space(3))) void*)(&sB[buf][e]), 16, 0, 0);
    }
  };

  stage(0, 0);
  for (int t = 0; t < nt; ++t) {
    const int cur = t & 1;
    __syncthreads();
    if (t + 1 < nt) stage(cur ^ 1, t + 1);
    const __hip_bfloat16* pa = sA[cur];
    const __hip_bfloat16* pb = sB[cur];
    short8 af[4], bfr[4];
    const int gsw = (lhi ^ (llo & 3)) << 3;  // swizzled granule offset (elems)
#pragma unroll
    for (int i = 0; i < 4; ++i) {
      af[i]  = *reinterpret_cast<const short8*>(pa + (wr + i * 16 + llo) * 32 + gsw);
      bfr[i] = *reinterpret_cast<const short8*>(pb + (wc + i * 16 + llo) * 32 + gsw);
    }
#pragma unroll
    for (int mi = 0; mi < 4; ++mi)
#pragma unroll
      for (int ni = 0; ni < 4; ++ni)
        acc[mi][ni] = __builtin_amdgcn_mfma_f32_16x16x32_bf16(af[mi], bfr[ni], acc[mi][ni], 0, 0, 0);
  }

#pragma unroll
  for (int mi = 0; mi < 4; ++mi) {
#pragma unroll
    for (int ni = 0; ni < 4; ++ni) {
      const int row = m0 + wr + mi * 16 + lhi * 4;
      const int col = n0 + wc + ni * 16 + llo;
      const float bc = bias[col];
      float qs = 1.0f;
      if (SCALE_Q) qs = ((col % 192) < 64) ? 0.125f : 1.0f;
#pragma unroll
      for (int j = 0; j < 4; ++j) {
        float v = acc[mi][ni][j] + bc;
        if (SCALE_Q) v *= qs;
        if (GELU_ACT) v = gelu_tanh(v);
        if (ADD_RES) v += res[(size_t)(row + j) * N + col];
        if (OUT_F32) outF[(size_t)(row + j) * N + col] = v;
        else outB[(size_t)(row + j) * N + col] = __float2bfloat16(v);
      }
    }
  }
}

// ---------------- 256^2 8-wave pipelined bf16 GEMM (T2+T3+T4+T5) ----------
// BM=BN=256, BK=64, 512 thr = 8 waves (2M x 4N), per-wave C = 128x64.
// LDS rows of 64 bf16 = 128B = 8 granules; slot s = g ^ (r&7) via pre-swizzled
// global source (write side linear) + XOR'd read addr -> 16-way conflicts
// become 2-way (free). Counted vmcnt(2): loads stay in flight across barriers.
template <int GELU_ACT, int SCALE_Q>
__global__ __launch_bounds__(512, 2) void gemm256(
    const __hip_bfloat16* __restrict__ A, const __hip_bfloat16* __restrict__ Bt,
    const float* __restrict__ bias, __hip_bfloat16* __restrict__ outB,
    int M, int N, int K) {
  __shared__ __align__(16) __hip_bfloat16 sA[2][256 * 64];
  __shared__ __align__(16) __hip_bfloat16 sB[2][256 * 64];
  const int tid = threadIdx.x;
  const int w = tid >> 6, l = tid & 63;
  const int lhi = l >> 4, llo = l & 15;
  const int gx = gridDim.x;
  int wg = blockIdx.y * gx + blockIdx.x;
  const int cpx = (gx * gridDim.y) >> 3;
  wg = (wg & 7) * cpx + (wg >> 3);
  const int m0 = (wg / gx) * 256, n0 = (wg % gx) * 256;
  const int wr = (w >> 2) * 128;  // 2 M-halves
  const int wc = (w & 3) * 64;    // 4 N-quarters
  f32x4 acc[8][4];
#pragma unroll
  for (int i = 0; i < 8; ++i)
#pragma unroll
    for (int j = 0; j < 4; ++j) acc[i][j] = zero4();

  const int nt = K >> 6;
  // lane writes LDS slot (r = (u&3)*64 + tid>>3, s = tid&7) linearly; it must
  // carry data granule s ^ (r&7) -> permute the SOURCE granule.
  const int cswz = (((tid & 7) ^ ((tid >> 3) & 7)) << 3);
  auto stageU = [&](int buf, int t, int u) {
    const int k0 = t << 6;
    const int r = ((u & 3) << 6) + (tid >> 3);
    const int e = ((u & 3) << 12) + (tid << 3);
    if (u < 4)
      __builtin_amdgcn_global_load_lds(
          (const __attribute__((address_space(1))) void*)(A + (size_t)(m0 + r) * K + k0 + cswz),
          (__attribute__((address_space(3))) void*)(&sA[buf][e]), 16, 0, 0);
    else
      __builtin_amdgcn_global_load_lds(
          (const __attribute__((address_space(1))) void*)(Bt + (size_t)(n0 + r) * K + k0 + cswz),
          (__attribute__((address_space(3))) void*)(&sB[buf][e]), 16, 0, 0);
  };

#pragma unroll
  for (int u = 0; u < 8; ++u) stageU(0, 0, u);  // prologue: tile 0

  for (int t = 0; t < nt; ++t) {
    const int b = t & 1;
    __builtin_amdgcn_s_barrier();  // all waves done reading buf b^1 (tile t-1)
    if (t + 1 < nt) {
      stageU(b ^ 1, t + 1, 0);
      stageU(b ^ 1, t + 1, 1);
      asm volatile("s_waitcnt vmcnt(2)" ::: "memory");  // tile t landed; 2 in flight
    } else {
      asm volatile("s_waitcnt vmcnt(0)" ::: "memory");
    }
    __builtin_amdgcn_s_barrier();  // cross-wave: tile t LDS valid
    const __hip_bfloat16* pa = sA[b];
    const __hip_bfloat16* pb = sB[b];
    const int rx = llo & 7;  // row&7 for this lane's reads
#pragma unroll
    for (int q = 0; q < 4; ++q) {
      const int mh = q >> 1, nh = q & 1;
      short8 af[4][2], bq[2][2];
#pragma unroll
      for (int i = 0; i < 4; ++i)
#pragma unroll
        for (int kk = 0; kk < 2; ++kk)
          af[i][kk] = *reinterpret_cast<const short8*>(
              pa + (wr + (mh * 4 + i) * 16 + llo) * 64 + (((kk * 4 + lhi) ^ rx) << 3));
#pragma unroll
      for (int n = 0; n < 2; ++n)
#pragma unroll
        for (int kk = 0; kk < 2; ++kk)
          bq[n][kk] = *reinterpret_cast<const short8*>(
              pb + (wc + (nh * 2 + n) * 16 + llo) * 64 + (((kk * 4 + lhi) ^ rx) << 3));
      if (t + 1 < nt && q < 3) {  // 6 remaining units under the MFMA phases
        stageU(b ^ 1, t + 1, 2 + q * 2);
        stageU(b ^ 1, t + 1, 3 + q * 2);
      }
      __builtin_amdgcn_s_setprio(1);
#pragma unroll
      for (int i = 0; i < 4; ++i)
#pragma unroll
        for (int n = 0; n < 2; ++n)
#pragma unroll
          for (int kk = 0; kk < 2; ++kk)
            acc[mh * 4 + i][nh * 2 + n] = __builtin_amdgcn_mfma_f32_16x16x32_bf16(
                af[i][kk], bq[n][kk], acc[mh * 4 + i][nh * 2 + n], 0, 0, 0);
      __builtin_amdgcn_s_setprio(0);
      if (q < 3) __builtin_amdgcn_s_barrier();  // phase lock (loop-top barrier covers q=3)
    }
  }

#pragma unroll
  for (int mi = 0; mi < 8; ++mi) {
#pragma unroll
    for (int ni = 0; ni < 4; ++ni) {
      const int row = m0 + wr + mi * 16 + lhi * 4;
      const int col = n0 + wc + ni * 16 + llo;
      const float bc = bias[col];
      float qs = 1.0f;
      if (SCALE_Q) qs = ((col % 192) < 64) ? 0.125f : 1.0f;
#pragma unroll
      for (int j = 0; j < 4; ++j) {
        float v = acc[mi][ni][j] + bc;
        if (SCALE_Q) v *= qs;
        if (GELU_ACT) v = gelu_tanh(v);
        outB[(size_t)(row + j) * N + col] = __float2bfloat16(v);
      }
    }
  }
}

// ---------------- V transpose: qkv V-region -> vt[b][h][d][T] ----------------
__global__ __launch_bounds__(256) void transpose_v(
    const __hip_bfloat16* __restrict__ qkv, __hip_bfloat16* __restrict__ vt) {
  const int t0 = blockIdx.x * 64, h = blockIdx.y, b = blockIdx.z;
  const size_t rb = (size_t)b * T_DIM;
  const size_t obase = ((size_t)(b * NH + h) * 64) * T_DIM;
  __shared__ unsigned short tl[64][64];
  const int tid = threadIdx.x;
#pragma unroll
  for (int k = 0; k < 2; ++k) {
    const int e = k * 2048 + tid * 8;
    const int tr = e >> 6, dc = e & 63;
    const short8 v =
        *reinterpret_cast<const short8*>(qkv + (rb + t0 + tr) * 3072 + h * 192 + 128 + dc);
    *reinterpret_cast<short8*>(&tl[tr][dc ^ ((tr & 7) << 3)]) = v;
  }
  __syncthreads();
#pragma unroll
  for (int k = 0; k < 2; ++k) {
    const int e = k * 2048 + tid * 8;
    const int dr = e >> 6, tc = e & 63;
    short8 o;
#pragma unroll
    for (int jj = 0; jj < 8; ++jj)
      o[jj] = (short)tl[tc + jj][dr ^ (((tc + jj) & 7) << 3)];
    *reinterpret_cast<short8*>(&vt[obase + (size_t)dr * T_DIM + t0 + tc]) = o;
  }
}

// ---------------- causal flash attention v6 (unchanged from round 10) --------
__global__ __launch_bounds__(256) void attn_fwd(
    const __hip_bfloat16* __restrict__ qkv, const __hip_bfloat16* __restrict__ vt,
    __hip_bfloat16* __restrict__ aout) {
  const int hb = blockIdx.x;
  const int h = hb & 15, b = hb >> 4;
  const int tid = threadIdx.x, w = tid >> 6, l = tid & 63;
  const int lhi = l >> 4, llo = l & 15;
  const int pr = w >> 1;               // pair slot in block (0,1)
  const int s = w & 1;                 // kv half
  const int p = blockIdx.y * 2 + pr;   // pair index 0..31
  const size_t rb = (size_t)b * T_DIM;
  const size_t vbase = ((size_t)(b * NH + h) * 64) * T_DIM;
  __shared__ __hip_bfloat16 sP[4][32][72];
  __shared__ float mrg[2][64][49];  // [pair][lane][32 O + 8 m + 8 l + pad]

  short8 onesb;
#pragma unroll
  for (int i = 0; i < 8; ++i) onesb[i] = (short)0x3F80;  // bf16 1.0

#pragma unroll
  for (int half = 0; half < 2; ++half) {
    const int tile = half ? (63 - p) : p;  // 32-row q tile, 0..63
    const int q0 = tile * 32;
    const int nkv = (tile >> 1) + 1;       // kv-tiles of 64
    const int base = (tile & 1) << 5;      // diag offset: 0 or 32
    const int kt_begin = s ? (nkv >> 1) : 0;
    const int kt_end   = s ? nkv : (nkv >> 1);

    short8 qf[2][2];
#pragma unroll
    for (int mf = 0; mf < 2; ++mf) {
      const __hip_bfloat16* qp =
          qkv + ((rb + q0 + mf * 16 + llo) * 3072 + h * 192 + lhi * 8);
      qf[mf][0] = *reinterpret_cast<const short8*>(qp);
      qf[mf][1] = *reinterpret_cast<const short8*>(qp + 32);
    }
    float mrun[2][4], lrun[2][4];
    f32x4 oacc[2][4];
#pragma unroll
    for (int mf = 0; mf < 2; ++mf)
#pragma unroll
      for (int j = 0; j < 4; ++j) { mrun[mf][j] = -1e30f; lrun[mf][j] = 0.f; }
#pragma unroll
    for (int mf = 0; mf < 2; ++mf)
#pragma unroll
      for (int di = 0; di < 4; ++di) oacc[mf][di] = zero4();

    auto loadK = [&](short8 (&dst)[4][2], int k0) {
#pragma unroll
      for (int ni = 0; ni < 4; ++ni) {
        const __hip_bfloat16* kp =
            qkv + ((rb + k0 + ni * 16 + llo) * 3072 + h * 192 + 64 + lhi * 8);
        dst[ni][0] = *reinterpret_cast<const short8*>(kp);
        dst[ni][1] = *reinterpret_cast<const short8*>(kp + 32);
      }
    };

    auto step = [&](short8 (&cK)[4][2], short8 (&nK)[4][2], int kt) {
      const bool diag = (kt == nkv - 1);
      const bool evendiag = diag && (base == 0);  // ni>=2 / k>=32 dead
      // S = Q K^T
      f32x4 sc[2][4];
      __builtin_amdgcn_s_setprio(1);
#pragma unroll
      for (int mf = 0; mf < 2; ++mf)
#pragma unroll
        for (int ni = 0; ni < 4; ++ni) {
          sc[mf][ni] = zero4();
          if (!evendiag || ni < 2) {
            sc[mf][ni] =
                __builtin_amdgcn_mfma_f32_16x16x32_bf16(qf[mf][0], cK[ni][0], sc[mf][ni], 0, 0, 0);
            sc[mf][ni] =
                __builtin_amdgcn_mfma_f32_16x16x32_bf16(qf[mf][1], cK[ni][1], sc[mf][ni], 0, 0, 0);
          }
        }
      __builtin_amdgcn_s_setprio(0);
      // prefetch next K tile
      if (kt + 1 < kt_end) loadK(nK, (kt + 1) * 64);
      // V for THIS step (L2 latency hides under softmax)
      short8 vCur[4][2];
#pragma unroll
      for (int di = 0; di < 4; ++di) {
        const __hip_bfloat16* vp =
            vt + (vbase + (size_t)(di * 16 + llo) * T_DIM + kt * 64 + lhi * 8);
        vCur[di][0] = *reinterpret_cast<const short8*>(vp);
        vCur[di][1] = *reinterpret_cast<const short8*>(vp + 32);
      }
      // online softmax
      float corr[2][4];
#pragma unroll
      for (int mf = 0; mf < 2; ++mf)
#pragma unroll
        for (int j = 0; j < 4; ++j) {
          const int ql = mf * 16 + lhi * 4 + j;
          float sv[4];
#pragma unroll
          for (int ni = 0; ni < 4; ++ni) {
            float sval = sc[mf][ni][j];
            if (diag) sval = (ni * 16 + llo <= base + ql) ? sval : -1e30f;
            sv[ni] = sval;
          }
          float mx = fmaxf(fmaxf(sv[0], sv[1]), fmaxf(sv[2], sv[3]));
#pragma unroll
          for (int d = 1; d < 16; d <<= 1) mx = fmaxf(mx, __shfl_xor(mx, d));
          const float mnew = fmaxf(mrun[mf][j], mx);
          const float c = __expf(mrun[mf][j] - mnew);
          mrun[mf][j] = mnew;
          corr[mf][j] = c;
#pragma unroll
          for (int ni = 0; ni < 4; ++ni)
            sP[w][mf * 16 + lhi * 4 + j][ni * 16 + llo] = __float2bfloat16(__expf(sv[ni] - mnew));
#pragma unroll
          for (int di = 0; di < 4; ++di) oacc[mf][di][j] *= c;
        }
      asm volatile("s_waitcnt lgkmcnt(0)" ::: "memory");
      // O += P V ; l += P 1
      __builtin_amdgcn_s_setprio(1);
#pragma unroll
      for (int mf = 0; mf < 2; ++mf) {
        const short8 pf0 = *reinterpret_cast<const short8*>(&sP[w][mf * 16 + llo][lhi * 8]);
        const short8 pf1 = *reinterpret_cast<const short8*>(&sP[w][mf * 16 + llo][32 + lhi * 8]);
        f32x4 lacc = zero4();
        lacc = __builtin_amdgcn_mfma_f32_16x16x32_bf16(pf0, onesb, lacc, 0, 0, 0);
        if (!evendiag)
          lacc = __builtin_amdgcn_mfma_f32_16x16x32_bf16(pf1, onesb, lacc, 0, 0, 0);
#pragma unroll
        for (int di = 0; di < 4; ++di) {
          oacc[mf][di] =
              __builtin_amdgcn_mfma_f32_16x16x32_bf16(pf0, vCur[di][0], oacc[mf][di], 0, 0, 0);
          if (!evendiag)
            oacc[mf][di] =
                __builtin_amdgcn_mfma_f32_16x16x32_bf16(pf1, vCur[di][1], oacc[mf][di], 0, 0, 0);
        }
#pragma unroll
        for (int j = 0; j < 4; ++j)
          lrun[mf][j] = lrun[mf][j] * corr[mf][j] + lacc[j];
      }
      __builtin_amdgcn_s_setprio(0);
    };

    short8 kA[4][2], kB[4][2];
    if (kt_begin < kt_end) loadK(kA, kt_begin * 64);
    for (int kt = kt_begin; kt < kt_end; ++kt) {
      if ((kt - kt_begin) & 1) step(kB, kA, kt);
      else                     step(kA, kB, kt);
    }

    // ---- merge the two kv-halves (flash-decoding combine) ----
    if (s == 0) {
      float* dst = &mrg[pr][l][0];
#pragma unroll
      for (int mf = 0; mf < 2; ++mf)
#pragma unroll
        for (int di = 0; di < 4; ++di)
#pragma unroll
          for (int j = 0; j < 4; ++j) dst[(mf * 4 + di) * 4 + j] = oacc[mf][di][j];
#pragma unroll
      for (int mf = 0; mf < 2; ++mf)
#pragma unroll
        for (int j = 0; j < 4; ++j) {
          dst[32 + mf * 4 + j] = mrun[mf][j];
          dst[40 + mf * 4 + j] = lrun[mf][j];
        }
    }
    __syncthreads();
    if (s == 1) {
      const float* src = &mrg[pr][l][0];
#pragma unroll
      for (int mf = 0; mf < 2; ++mf)
#pragma unroll
        for (int j = 0; j < 4; ++j) {
          const float m0 = src[32 + mf * 4 + j], l0 = src[40 + mf * 4 + j];
          const float m1 = mrun[mf][j], l1 = lrun[mf][j];
          const float mm = fmaxf(m0, m1);
          const float a0 = __expf(m0 - mm), a1 = __expf(m1 - mm);
          const float linv = 1.0f / (l0 * a0 + l1 * a1);
          const size_t row = rb + q0 + mf * 16 + lhi * 4 + j;
#pragma unroll
          for (int di = 0; di < 4; ++di) {
            const float o = (src[(mf * 4 + di) * 4 + j] * a0 + oacc[mf][di][j] * a1) * linv;
            aout[row * 1024 + h * 64 + di * 16 + llo] = __float2bfloat16(o);
          }
        }
    }
    __syncthreads();
  }
}

// ---------------- launch ----------------
extern "C" void kernel_launch(void* const* d_in, const int* in_sizes, int n_in,
                              void* d_out, int out_size, void* d_ws, size_t ws_size,
                              hipStream_t stream) {
  (void)in_sizes; (void)n_in; (void)out_size; (void)ws_size;
  const float* x      = (const float*)d_in[0];
  const float* ln1_g  = (const float*)d_in[1];
  const float* ln1_b  = (const float*)d_in[2];
  const float* w_qkv  = (const float*)d_in[3];
  const float* b_qkv  = (const float*)d_in[4];
  const float* w_out  = (const float*)d_in[5];
  const float* b_out  = (const float*)d_in[6];
  const float* ln2_g  = (const float*)d_in[7];
  const float* ln2_b  = (const float*)d_in[8];
  const float* w_fc   = (const float*)d_in[9];
  const float* b_fc   = (const float*)d_in[10];
  const float* w_proj = (const float*)d_in[11];
  const float* b_proj = (const float*)d_in[12];
  float* out = (float*)d_out;

  const int M = 2 * T_DIM;  // 4096 rows
  char* wsp = (char*)d_ws;
  size_t off = 0;
  auto carve = [&](size_t bytes) {
    void* p = wsp + off;
    off += (bytes + 255) & ~(size_t)255;
    return p;
  };
  __hip_bfloat16* wt_qkv  = (__hip_bfloat16*)carve((size_t)3072 * 1024 * 2);
  __hip_bfloat16* wt_out  = (__hip_bfloat16*)carve((size_t)1024 * 1024 * 2);
  __hip_bfloat16* wt_fc   = (__hip_bfloat16*)carve((size_t)4096 * 1024 * 2);
  __hip_bfloat16* wt_proj = (__hip_bfloat16*)carve((size_t)1024 * 4096 * 2);
  __hip_bfloat16* ln1o    = (__hip_bfloat16*)carve((size_t)M * 1024 * 2);
  __hip_bfloat16* qkvb    = (__hip_bfloat16*)carve((size_t)M * 3072 * 2);
  __hip_bfloat16* vtb     = (__hip_bfloat16*)carve((size_t)2 * NH * 64 * T_DIM * 2);
  __hip_bfloat16* attnb   = (__hip_bfloat16*)carve((size_t)M * 1024 * 2);
  float*          x2      = (float*)carve((size_t)M * 1024 * 4);
  __hip_bfloat16* h1      = (__hip_bfloat16*)carve((size_t)M * 4096 * 2);
  __hip_bfloat16* ln2o    = ln1o;  // ln1 output dead after QKV GEMM; reuse

  // weights -> bf16 [N][K]
  transpose_f32_to_bf16<<<dim3(3072 / 64, 1024 / 64), 256, 0, stream>>>(w_qkv, wt_qkv, 1024, 3072);
  transpose_f32_to_bf16<<<dim3(1024 / 64, 1024 / 64), 256, 0, stream>>>(w_out, wt_out, 1024, 1024);
  transpose_f32_to_bf16<<<dim3(4096 / 64, 1024 / 64), 256, 0, stream>>>(w_fc, wt_fc, 1024, 4096);
  transpose_f32_to_bf16<<<dim3(1024 / 64, 4096 / 64), 256, 0, stream>>>(w_proj, wt_proj, 4096, 1024);

  layernorm_bf16<<<M / 4, 256, 0, stream>>>(x, ln1_g, ln1_b, ln1o);
  gemm256<0, 1><<<dim3(3072 / 256, M / 256), 512, 0, stream>>>(
      ln1o, wt_qkv, b_qkv, qkvb, M, 3072, 1024);
  transpose_v<<<dim3(T_DIM / 64, NH, 2), 256, 0, stream>>>(qkvb, vtb);
  attn_fwd<<<dim3(32, 16), 256, 0, stream>>>(qkvb, vtb, attnb);
  gemm_bt<0, 1, 1, 0><<<dim3(1024 / 128, M / 128), 256, 0, stream>>>(
      attnb, wt_out, b_out, x, x2, nullptr, M, 1024, 1024);
  layernorm_bf16<<<M / 4, 256, 0, stream>>>(x2, ln2_g, ln2_b, ln2o);
  gemm256<1, 0><<<dim3(4096 / 256, M / 256), 512, 0, stream>>>(
      ln2o, wt_fc, b_fc, h1, M, 4096, 1024);
  gemm_bt<0, 1, 1, 0><<<dim3(1024 / 128, M / 128), 256, 0, stream>>>(
      h1, wt_proj, b_proj, x2, out, nullptr, M, 1024, 4096);
}

// Round 14
// 319.053 us; speedup vs baseline: 1.1894x; 1.0290x over previous
//
#include <hip/hip_runtime.h>
#include <hip/hip_bf16.h>

// Transformer block forward: B=2, T=2048, E=1024, H=16, D=64.
// Pipeline: prep (4 weight transposes + LN1 fused, segmented grid) |
//           QKV GEMM (128^2 swz) | V transpose | flash attn v7 (v6+defer-max) |
//           out-proj+res | LN2 | FC+GELU | proj+res.  All GEMMs 128^2 swizzled.

#define T_DIM 2048
#define E_DIM 1024
#define NH 16

using short8 = __attribute__((__ext_vector_type__(8))) short;
using f32x4  = __attribute__((__ext_vector_type__(4))) float;

static __device__ __forceinline__ f32x4 zero4() {
  f32x4 z = {0.f, 0.f, 0.f, 0.f};
  return z;
}

static __device__ __forceinline__ unsigned short f2bfbits(float f) {
  __hip_bfloat16 h = __float2bfloat16(f);
  return *reinterpret_cast<unsigned short*>(&h);
}

static __device__ __forceinline__ float gelu_tanh(float x) {
  float z = 0.7978845608028654f * (x + 0.044715f * x * x * x);
  float e = __expf(2.0f * z);
  float th = 1.0f - 2.0f / (e + 1.0f);
  return 0.5f * x * (1.0f + th);
}

// ---------------- prep: 4 weight transposes (f32 [K][N] -> bf16 [N][K]) + LN1 ----
// grid.x = 3072 transpose tiles + 1024 LN1 row-groups. One launch replaces five.
__global__ __launch_bounds__(256) void prep(
    const float* __restrict__ w_qkv, const float* __restrict__ w_out,
    const float* __restrict__ w_fc, const float* __restrict__ w_proj,
    __hip_bfloat16* __restrict__ t_qkv, __hip_bfloat16* __restrict__ t_out,
    __hip_bfloat16* __restrict__ t_fc, __hip_bfloat16* __restrict__ t_proj,
    const float* __restrict__ x, const float* __restrict__ g,
    const float* __restrict__ bb, __hip_bfloat16* __restrict__ ln1o) {
  __shared__ float tl[64][65];
  const int id = blockIdx.x;
  const int t = threadIdx.x;
  if (id < 3072) {
    const float* in;
    __hip_bfloat16* out;
    int K, N, bx, by;
    if (id < 768) {
      in = w_qkv; out = t_qkv; K = 1024; N = 3072; bx = id % 48; by = id / 48;
    } else if (id < 1024) {
      const int i = id - 768;
      in = w_out; out = t_out; K = 1024; N = 1024; bx = i % 16; by = i / 16;
    } else if (id < 2048) {
      const int i = id - 1024;
      in = w_fc; out = t_fc; K = 1024; N = 4096; bx = i % 64; by = i / 64;
    } else {
      const int i = id - 2048;
      in = w_proj; out = t_proj; K = 4096; N = 1024; bx = i % 16; by = i / 16;
    }
    const int n0 = bx * 64, k0 = by * 64;
    const int rr = t >> 4;        // 0..15
    const int cc = (t & 15) * 4;  // 0..60
#pragma unroll
    for (int i = 0; i < 4; ++i) {
      const int row = rr + i * 16;
      const float4 v = *reinterpret_cast<const float4*>(&in[(size_t)(k0 + row) * N + n0 + cc]);
      tl[row][cc] = v.x; tl[row][cc + 1] = v.y; tl[row][cc + 2] = v.z; tl[row][cc + 3] = v.w;
    }
    __syncthreads();
#pragma unroll
    for (int i = 0; i < 4; ++i) {
      const int row = rr + i * 16;  // output row (n)
      ushort4 pk;
      pk.x = f2bfbits(tl[cc + 0][row]);
      pk.y = f2bfbits(tl[cc + 1][row]);
      pk.z = f2bfbits(tl[cc + 2][row]);
      pk.w = f2bfbits(tl[cc + 3][row]);
      *reinterpret_cast<ushort4*>(&out[(size_t)(n0 + row) * K + k0 + cc]) = pk;
    }
  } else {
    // LN1: rows of 1024, f32 in -> bf16 out
    const int lane = t & 63;
    const int row = (id - 3072) * 4 + (t >> 6);
    const float* xr = x + (size_t)row * E_DIM;
    float4 v[4];
    float s = 0.f, s2 = 0.f;
#pragma unroll
    for (int i = 0; i < 4; ++i) {
      v[i] = *reinterpret_cast<const float4*>(&xr[(i * 64 + lane) * 4]);
      s  += v[i].x + v[i].y + v[i].z + v[i].w;
      s2 += v[i].x * v[i].x + v[i].y * v[i].y + v[i].z * v[i].z + v[i].w * v[i].w;
    }
#pragma unroll
    for (int m = 1; m < 64; m <<= 1) { s += __shfl_xor(s, m); s2 += __shfl_xor(s2, m); }
    const float mu = s * (1.0f / E_DIM);
    const float var = s2 * (1.0f / E_DIM) - mu * mu;
    const float rstd = rsqrtf(var + 1e-5f);
    __hip_bfloat16* orow = ln1o + (size_t)row * E_DIM;
#pragma unroll
    for (int i = 0; i < 4; ++i) {
      const int col = (i * 64 + lane) * 4;
      const float4 gv = *reinterpret_cast<const float4*>(&g[col]);
      const float4 bv = *reinterpret_cast<const float4*>(&bb[col]);
      ushort4 pk;
      pk.x = f2bfbits((v[i].x - mu) * rstd * gv.x + bv.x);
      pk.y = f2bfbits((v[i].y - mu) * rstd * gv.y + bv.y);
      pk.z = f2bfbits((v[i].z - mu) * rstd * gv.z + bv.z);
      pk.w = f2bfbits((v[i].w - mu) * rstd * gv.w + bv.w);
      *reinterpret_cast<ushort4*>(&orow[col]) = pk;
    }
  }
}

// ---------------- LayerNorm rows of 1024, f32 in -> bf16 out (LN2) ----------------
__global__ __launch_bounds__(256) void layernorm_bf16(
    const float* __restrict__ x, const float* __restrict__ g, const float* __restrict__ bb,
    __hip_bfloat16* __restrict__ out) {
  const int lane = threadIdx.x & 63;
  const int row = blockIdx.x * 4 + (threadIdx.x >> 6);
  const float* xr = x + (size_t)row * E_DIM;
  float4 v[4];
  float s = 0.f, s2 = 0.f;
#pragma unroll
  for (int i = 0; i < 4; ++i) {
    v[i] = *reinterpret_cast<const float4*>(&xr[(i * 64 + lane) * 4]);
    s  += v[i].x + v[i].y + v[i].z + v[i].w;
    s2 += v[i].x * v[i].x + v[i].y * v[i].y + v[i].z * v[i].z + v[i].w * v[i].w;
  }
#pragma unroll
  for (int m = 1; m < 64; m <<= 1) { s += __shfl_xor(s, m); s2 += __shfl_xor(s2, m); }
  const float mu = s * (1.0f / E_DIM);
  const float var = s2 * (1.0f / E_DIM) - mu * mu;
  const float rstd = rsqrtf(var + 1e-5f);
  __hip_bfloat16* orow = out + (size_t)row * E_DIM;
#pragma unroll
  for (int i = 0; i < 4; ++i) {
    const int col = (i * 64 + lane) * 4;
    const float4 gv = *reinterpret_cast<const float4*>(&g[col]);
    const float4 bv = *reinterpret_cast<const float4*>(&bb[col]);
    ushort4 pk;
    pk.x = f2bfbits((v[i].x - mu) * rstd * gv.x + bv.x);
    pk.y = f2bfbits((v[i].y - mu) * rstd * gv.y + bv.y);
    pk.z = f2bfbits((v[i].z - mu) * rstd * gv.z + bv.z);
    pk.w = f2bfbits((v[i].w - mu) * rstd * gv.w + bv.w);
    *reinterpret_cast<ushort4*>(&orow[col]) = pk;
  }
}

// ---------------- 128^2 bf16 GEMM, T2-swizzled LDS ----------------
template <int GELU_ACT, int ADD_RES, int OUT_F32, int SCALE_Q>
__global__ __launch_bounds__(256, 2) void gemm_bt(
    const __hip_bfloat16* __restrict__ A, const __hip_bfloat16* __restrict__ Bt,
    const float* __restrict__ bias, const float* __restrict__ res,
    float* __restrict__ outF, __hip_bfloat16* __restrict__ outB,
    int M, int N, int K) {
  __shared__ __hip_bfloat16 sA[2][128 * 32];
  __shared__ __hip_bfloat16 sB[2][128 * 32];
  const int tid = threadIdx.x;
  const int w = tid >> 6, l = tid & 63;
  const int lhi = l >> 4, llo = l & 15;
  const int gx = gridDim.x;
  int wg = blockIdx.y * gx + blockIdx.x;
  const int cpx = (gx * gridDim.y) >> 3;
  wg = (wg & 7) * cpx + (wg >> 3);
  const int m0 = (wg / gx) * 128, n0 = (wg % gx) * 128;
  const int wr = (w >> 1) * 64, wc = (w & 1) * 64;
  f32x4 acc[4][4];
#pragma unroll
  for (int i = 0; i < 4; ++i)
#pragma unroll
    for (int j = 0; j < 4; ++j) acc[i][j] = zero4();

  const int nt = K >> 5;
  const int cswz = (((tid & 3) ^ ((tid >> 2) & 3)) << 3);
  auto stage = [&](int buf, int t) {
    const int k0 = t << 5;
#pragma unroll
    for (int i = 0; i < 2; ++i) {
      const int r = i * 64 + (tid >> 2);
      const int e = i * 2048 + tid * 8;
      __builtin_amdgcn_global_load_lds(
          (const __attribute__((address_space(1))) void*)(A + (size_t)(m0 + r) * K + k0 + cswz),
          (__attribute__((address_space(3))) void*)(&sA[buf][e]), 16, 0, 0);
      __builtin_amdgcn_global_load_lds(
          (const __attribute__((address_space(1))) void*)(Bt + (size_t)(n0 + r) * K + k0 + cswz),
          (__attribute__((address_space(3))) void*)(&sB[buf][e]), 16, 0, 0);
    }
  };

  stage(0, 0);
  for (int t = 0; t < nt; ++t) {
    const int cur = t & 1;
    __syncthreads();
    if (t + 1 < nt) stage(cur ^ 1, t + 1);
    const __hip_bfloat16* pa = sA[cur];
    const __hip_bfloat16* pb = sB[cur];
    short8 af[4], bfr[4];
    const int gsw = (lhi ^ (llo & 3)) << 3;
#pragma unroll
    for (int i = 0; i < 4; ++i) {
      af[i]  = *reinterpret_cast<const short8*>(pa + (wr + i * 16 + llo) * 32 + gsw);
      bfr[i] = *reinterpret_cast<const short8*>(pb + (wc + i * 16 + llo) * 32 + gsw);
    }
#pragma unroll
    for (int mi = 0; mi < 4; ++mi)
#pragma unroll
      for (int ni = 0; ni < 4; ++ni)
        acc[mi][ni] = __builtin_amdgcn_mfma_f32_16x16x32_bf16(af[mi], bfr[ni], acc[mi][ni], 0, 0, 0);
  }

#pragma unroll
  for (int mi = 0; mi < 4; ++mi) {
#pragma unroll
    for (int ni = 0; ni < 4; ++ni) {
      const int row = m0 + wr + mi * 16 + lhi * 4;
      const int col = n0 + wc + ni * 16 + llo;
      const float bc = bias[col];
      float qs = 1.0f;
      if (SCALE_Q) qs = ((col % 192) < 64) ? 0.125f : 1.0f;
#pragma unroll
      for (int j = 0; j < 4; ++j) {
        float v = acc[mi][ni][j] + bc;
        if (SCALE_Q) v *= qs;
        if (GELU_ACT) v = gelu_tanh(v);
        if (ADD_RES) v += res[(size_t)(row + j) * N + col];
        if (OUT_F32) outF[(size_t)(row + j) * N + col] = v;
        else outB[(size_t)(row + j) * N + col] = __float2bfloat16(v);
      }
    }
  }
}

// ---------------- V transpose: qkv V-region -> vt[b][h][d][T] ----------------
__global__ __launch_bounds__(256) void transpose_v(
    const __hip_bfloat16* __restrict__ qkv, __hip_bfloat16* __restrict__ vt) {
  const int t0 = blockIdx.x * 64, h = blockIdx.y, b = blockIdx.z;
  const size_t rb = (size_t)b * T_DIM;
  const size_t obase = ((size_t)(b * NH + h) * 64) * T_DIM;
  __shared__ unsigned short tl[64][64];
  const int tid = threadIdx.x;
#pragma unroll
  for (int k = 0; k < 2; ++k) {
    const int e = k * 2048 + tid * 8;
    const int tr = e >> 6, dc = e & 63;
    const short8 v =
        *reinterpret_cast<const short8*>(qkv + (rb + t0 + tr) * 3072 + h * 192 + 128 + dc);
    *reinterpret_cast<short8*>(&tl[tr][dc ^ ((tr & 7) << 3)]) = v;
  }
  __syncthreads();
#pragma unroll
  for (int k = 0; k < 2; ++k) {
    const int e = k * 2048 + tid * 8;
    const int dr = e >> 6, tc = e & 63;
    short8 o;
#pragma unroll
    for (int jj = 0; jj < 8; ++jj)
      o[jj] = (short)tl[tc + jj][dr ^ (((tc + jj) & 7) << 3)];
    *reinterpret_cast<short8*>(&vt[obase + (size_t)dr * T_DIM + t0 + tc]) = o;
  }
}

// ---------------- causal flash attention v7 (v6 + defer-max T13) --------
// Defer-max: when every row's tile-max is <= m_run + 8 (wave-uniform ballot),
// keep the old running max -> skip the O-rescale and corr chain. P bounded by
// e^8, safe in bf16/f32 (guide T13, THR=8, refcheck'd).
__global__ __launch_bounds__(256) void attn_fwd(
    const __hip_bfloat16* __restrict__ qkv, const __hip_bfloat16* __restrict__ vt,
    __hip_bfloat16* __restrict__ aout) {
  const int hb = blockIdx.x;
  const int h = hb & 15, b = hb >> 4;
  const int tid = threadIdx.x, w = tid >> 6, l = tid & 63;
  const int lhi = l >> 4, llo = l & 15;
  const int pr = w >> 1;               // pair slot in block (0,1)
  const int s = w & 1;                 // kv half
  const int p = blockIdx.y * 2 + pr;   // pair index 0..31
  const size_t rb = (size_t)b * T_DIM;
  const size_t vbase = ((size_t)(b * NH + h) * 64) * T_DIM;
  __shared__ __hip_bfloat16 sP[4][32][72];
  __shared__ float mrg[2][64][49];  // [pair][lane][32 O + 8 m + 8 l + pad]

  short8 onesb;
#pragma unroll
  for (int i = 0; i < 8; ++i) onesb[i] = (short)0x3F80;  // bf16 1.0

#pragma unroll
  for (int half = 0; half < 2; ++half) {
    const int tile = half ? (63 - p) : p;  // 32-row q tile, 0..63
    const int q0 = tile * 32;
    const int nkv = (tile >> 1) + 1;       // kv-tiles of 64
    const int base = (tile & 1) << 5;      // diag offset: 0 or 32
    const int kt_begin = s ? (nkv >> 1) : 0;
    const int kt_end   = s ? nkv : (nkv >> 1);

    short8 qf[2][2];
#pragma unroll
    for (int mf = 0; mf < 2; ++mf) {
      const __hip_bfloat16* qp =
          qkv + ((rb + q0 + mf * 16 + llo) * 3072 + h * 192 + lhi * 8);
      qf[mf][0] = *reinterpret_cast<const short8*>(qp);
      qf[mf][1] = *reinterpret_cast<const short8*>(qp + 32);
    }
    float mrun[2][4], lrun[2][4];
    f32x4 oacc[2][4];
#pragma unroll
    for (int mf = 0; mf < 2; ++mf)
#pragma unroll
      for (int j = 0; j < 4; ++j) { mrun[mf][j] = -1e30f; lrun[mf][j] = 0.f; }
#pragma unroll
    for (int mf = 0; mf < 2; ++mf)
#pragma unroll
      for (int di = 0; di < 4; ++di) oacc[mf][di] = zero4();

    auto loadK = [&](short8 (&dst)[4][2], int k0) {
#pragma unroll
      for (int ni = 0; ni < 4; ++ni) {
        const __hip_bfloat16* kp =
            qkv + ((rb + k0 + ni * 16 + llo) * 3072 + h * 192 + 64 + lhi * 8);
        dst[ni][0] = *reinterpret_cast<const short8*>(kp);
        dst[ni][1] = *reinterpret_cast<const short8*>(kp + 32);
      }
    };

    auto step = [&](short8 (&cK)[4][2], short8 (&nK)[4][2], int kt) {
      const bool diag = (kt == nkv - 1);
      const bool evendiag = diag && (base == 0);  // ni>=2 / k>=32 dead
      // S = Q K^T
      f32x4 sc[2][4];
      __builtin_amdgcn_s_setprio(1);
#pragma unroll
      for (int mf = 0; mf < 2; ++mf)
#pragma unroll
        for (int ni = 0; ni < 4; ++ni) {
          sc[mf][ni] = zero4();
          if (!evendiag || ni < 2) {
            sc[mf][ni] =
                __builtin_amdgcn_mfma_f32_16x16x32_bf16(qf[mf][0], cK[ni][0], sc[mf][ni], 0, 0, 0);
            sc[mf][ni] =
                __builtin_amdgcn_mfma_f32_16x16x32_bf16(qf[mf][1], cK[ni][1], sc[mf][ni], 0, 0, 0);
          }
        }
      __builtin_amdgcn_s_setprio(0);
      // prefetch next K tile
      if (kt + 1 < kt_end) loadK(nK, (kt + 1) * 64);
      // V for THIS step (L2 latency hides under softmax)
      short8 vCur[4][2];
#pragma unroll
      for (int di = 0; di < 4; ++di) {
        const __hip_bfloat16* vp =
            vt + (vbase + (size_t)(di * 16 + llo) * T_DIM + kt * 64 + lhi * 8);
        vCur[di][0] = *reinterpret_cast<const short8*>(vp);
        vCur[di][1] = *reinterpret_cast<const short8*>(vp + 32);
      }
      // mask (in place) + per-row tile max + defer-max predicate
      float mx[2][4];
      bool ok = true;
#pragma unroll
      for (int mf = 0; mf < 2; ++mf)
#pragma unroll
        for (int j = 0; j < 4; ++j) {
          const int ql = mf * 16 + lhi * 4 + j;
#pragma unroll
          for (int ni = 0; ni < 4; ++ni) {
            float sval = sc[mf][ni][j];
            if (diag) sval = (ni * 16 + llo <= base + ql) ? sval : -1e30f;
            sc[mf][ni][j] = sval;
          }
          float m = fmaxf(fmaxf(sc[mf][0][j], sc[mf][1][j]),
                          fmaxf(sc[mf][2][j], sc[mf][3][j]));
#pragma unroll
          for (int d = 1; d < 16; d <<= 1) m = fmaxf(m, __shfl_xor(m, d));
          mx[mf][j] = m;
          ok = ok && (m <= mrun[mf][j] + 8.0f);
        }
      float corr[2][4];
      if (__all((int)ok)) {
        // fast path: no rescale, keep m_run
#pragma unroll
        for (int mf = 0; mf < 2; ++mf)
#pragma unroll
          for (int j = 0; j < 4; ++j) {
            corr[mf][j] = 1.0f;
#pragma unroll
            for (int ni = 0; ni < 4; ++ni)
              sP[w][mf * 16 + lhi * 4 + j][ni * 16 + llo] =
                  __float2bfloat16(__expf(sc[mf][ni][j] - mrun[mf][j]));
          }
      } else {
#pragma unroll
        for (int mf = 0; mf < 2; ++mf)
#pragma unroll
          for (int j = 0; j < 4; ++j) {
            const float mnew = fmaxf(mrun[mf][j], mx[mf][j]);
            const float c = __expf(mrun[mf][j] - mnew);
            mrun[mf][j] = mnew;
            corr[mf][j] = c;
#pragma unroll
            for (int ni = 0; ni < 4; ++ni)
              sP[w][mf * 16 + lhi * 4 + j][ni * 16 + llo] =
                  __float2bfloat16(__expf(sc[mf][ni][j] - mnew));
#pragma unroll
            for (int di = 0; di < 4; ++di) oacc[mf][di][j] *= c;
          }
      }
      asm volatile("s_waitcnt lgkmcnt(0)" ::: "memory");
      // O += P V ; l += P 1
      __builtin_amdgcn_s_setprio(1);
#pragma unroll
      for (int mf = 0; mf < 2; ++mf) {
        const short8 pf0 = *reinterpret_cast<const short8*>(&sP[w][mf * 16 + llo][lhi * 8]);
        const short8 pf1 = *reinterpret_cast<const short8*>(&sP[w][mf * 16 + llo][32 + lhi * 8]);
        f32x4 lacc = zero4();
        lacc = __builtin_amdgcn_mfma_f32_16x16x32_bf16(pf0, onesb, lacc, 0, 0, 0);
        if (!evendiag)
          lacc = __builtin_amdgcn_mfma_f32_16x16x32_bf16(pf1, onesb, lacc, 0, 0, 0);
#pragma unroll
        for (int di = 0; di < 4; ++di) {
          oacc[mf][di] =
              __builtin_amdgcn_mfma_f32_16x16x32_bf16(pf0, vCur[di][0], oacc[mf][di], 0, 0, 0);
          if (!evendiag)
            oacc[mf][di] =
                __builtin_amdgcn_mfma_f32_16x16x32_bf16(pf1, vCur[di][1], oacc[mf][di], 0, 0, 0);
        }
#pragma unroll
        for (int j = 0; j < 4; ++j)
          lrun[mf][j] = lrun[mf][j] * corr[mf][j] + lacc[j];
      }
      __builtin_amdgcn_s_setprio(0);
    };

    short8 kA[4][2], kB[4][2];
    if (kt_begin < kt_end) loadK(kA, kt_begin * 64);
    for (int kt = kt_begin; kt < kt_end; ++kt) {
      if ((kt - kt_begin) & 1) step(kB, kA, kt);
      else                     step(kA, kB, kt);
    }

    // ---- merge the two kv-halves (flash-decoding combine) ----
    if (s == 0) {
      float* dst = &mrg[pr][l][0];
#pragma unroll
      for (int mf = 0; mf < 2; ++mf)
#pragma unroll
        for (int di = 0; di < 4; ++di)
#pragma unroll
          for (int j = 0; j < 4; ++j) dst[(mf * 4 + di) * 4 + j] = oacc[mf][di][j];
#pragma unroll
      for (int mf = 0; mf < 2; ++mf)
#pragma unroll
        for (int j = 0; j < 4; ++j) {
          dst[32 + mf * 4 + j] = mrun[mf][j];
          dst[40 + mf * 4 + j] = lrun[mf][j];
        }
    }
    __syncthreads();
    if (s == 1) {
      const float* src = &mrg[pr][l][0];
#pragma unroll
      for (int mf = 0; mf < 2; ++mf)
#pragma unroll
        for (int j = 0; j < 4; ++j) {
          const float m0 = src[32 + mf * 4 + j], l0 = src[40 + mf * 4 + j];
          const float m1 = mrun[mf][j], l1 = lrun[mf][j];
          const float mm = fmaxf(m0, m1);
          const float a0 = __expf(m0 - mm), a1 = __expf(m1 - mm);
          const float linv = 1.0f / (l0 * a0 + l1 * a1);
          const size_t row = rb + q0 + mf * 16 + lhi * 4 + j;
#pragma unroll
          for (int di = 0; di < 4; ++di) {
            const float o = (src[(mf * 4 + di) * 4 + j] * a0 + oacc[mf][di][j] * a1) * linv;
            aout[row * 1024 + h * 64 + di * 16 + llo] = __float2bfloat16(o);
          }
        }
    }
    __syncthreads();
  }
}

// ---------------- launch ----------------
extern "C" void kernel_launch(void* const* d_in, const int* in_sizes, int n_in,
                              void* d_out, int out_size, void* d_ws, size_t ws_size,
                              hipStream_t stream) {
  (void)in_sizes; (void)n_in; (void)out_size; (void)ws_size;
  const float* x      = (const float*)d_in[0];
  const float* ln1_g  = (const float*)d_in[1];
  const float* ln1_b  = (const float*)d_in[2];
  const float* w_qkv  = (const float*)d_in[3];
  const float* b_qkv  = (const float*)d_in[4];
  const float* w_out  = (const float*)d_in[5];
  const float* b_out  = (const float*)d_in[6];
  const float* ln2_g  = (const float*)d_in[7];
  const float* ln2_b  = (const float*)d_in[8];
  const float* w_fc   = (const float*)d_in[9];
  const float* b_fc   = (const float*)d_in[10];
  const float* w_proj = (const float*)d_in[11];
  const float* b_proj = (const float*)d_in[12];
  float* out = (float*)d_out;

  const int M = 2 * T_DIM;  // 4096 rows
  char* wsp = (char*)d_ws;
  size_t off = 0;
  auto carve = [&](size_t bytes) {
    void* p = wsp + off;
    off += (bytes + 255) & ~(size_t)255;
    return p;
  };
  __hip_bfloat16* wt_qkv  = (__hip_bfloat16*)carve((size_t)3072 * 1024 * 2);
  __hip_bfloat16* wt_out  = (__hip_bfloat16*)carve((size_t)1024 * 1024 * 2);
  __hip_bfloat16* wt_fc   = (__hip_bfloat16*)carve((size_t)4096 * 1024 * 2);
  __hip_bfloat16* wt_proj = (__hip_bfloat16*)carve((size_t)1024 * 4096 * 2);
  __hip_bfloat16* ln1o    = (__hip_bfloat16*)carve((size_t)M * 1024 * 2);
  __hip_bfloat16* qkvb    = (__hip_bfloat16*)carve((size_t)M * 3072 * 2);
  __hip_bfloat16* vtb     = (__hip_bfloat16*)carve((size_t)2 * NH * 64 * T_DIM * 2);
  __hip_bfloat16* attnb   = (__hip_bfloat16*)carve((size_t)M * 1024 * 2);
  float*          x2      = (float*)carve((size_t)M * 1024 * 4);
  __hip_bfloat16* h1      = (__hip_bfloat16*)carve((size_t)M * 4096 * 2);
  __hip_bfloat16* ln2o    = ln1o;  // ln1 output dead after QKV GEMM; reuse

  // fused prologue: 4 weight transposes + LN1 in one launch
  prep<<<4096, 256, 0, stream>>>(w_qkv, w_out, w_fc, w_proj,
                                 wt_qkv, wt_out, wt_fc, wt_proj,
                                 x, ln1_g, ln1_b, ln1o);
  gemm_bt<0, 0, 0, 1><<<dim3(3072 / 128, M / 128), 256, 0, stream>>>(
      ln1o, wt_qkv, b_qkv, nullptr, nullptr, qkvb, M, 3072, 1024);
  transpose_v<<<dim3(T_DIM / 64, NH, 2), 256, 0, stream>>>(qkvb, vtb);
  attn_fwd<<<dim3(32, 16), 256, 0, stream>>>(qkvb, vtb, attnb);
  gemm_bt<0, 1, 1, 0><<<dim3(1024 / 128, M / 128), 256, 0, stream>>>(
      attnb, wt_out, b_out, x, x2, nullptr, M, 1024, 1024);
  layernorm_bf16<<<M / 4, 256, 0, stream>>>(x2, ln2_g, ln2_b, ln2o);
  gemm_bt<1, 0, 0, 0><<<dim3(4096 / 128, M / 128), 256, 0, stream>>>(
      ln2o, wt_fc, b_fc, nullptr, nullptr, h1, M, 4096, 1024);
  gemm_bt<0, 1, 1, 0><<<dim3(1024 / 128, M / 128), 256, 0, stream>>>(
      h1, wt_proj, b_proj, x2, out, nullptr, M, 1024, 4096);
}

// Round 15
// 314.065 us; speedup vs baseline: 1.2083x; 1.0159x over previous
//
#include <hip/hip_runtime.h>
#include <hip/hip_bf16.h>

// Transformer block forward: B=2, T=2048, E=1024, H=16, D=64.
// Pipeline: prep (4 weight transposes + LN1 fused) | QKV GEMM (128^2 swz, 3wv/EU) |
//           V transpose | flash attn v6 | out-proj+res | LN2 | FC+GELU | proj+res.

#define T_DIM 2048
#define E_DIM 1024
#define NH 16

using short8 = __attribute__((__ext_vector_type__(8))) short;
using f32x4  = __attribute__((__ext_vector_type__(4))) float;

static __device__ __forceinline__ f32x4 zero4() {
  f32x4 z = {0.f, 0.f, 0.f, 0.f};
  return z;
}

static __device__ __forceinline__ unsigned short f2bfbits(float f) {
  __hip_bfloat16 h = __float2bfloat16(f);
  return *reinterpret_cast<unsigned short*>(&h);
}

static __device__ __forceinline__ float gelu_tanh(float x) {
  float z = 0.7978845608028654f * (x + 0.044715f * x * x * x);
  float e = __expf(2.0f * z);
  float th = 1.0f - 2.0f / (e + 1.0f);
  return 0.5f * x * (1.0f + th);
}

// ---------------- prep: 4 weight transposes (f32 [K][N] -> bf16 [N][K]) + LN1 ----
__global__ __launch_bounds__(256) void prep(
    const float* __restrict__ w_qkv, const float* __restrict__ w_out,
    const float* __restrict__ w_fc, const float* __restrict__ w_proj,
    __hip_bfloat16* __restrict__ t_qkv, __hip_bfloat16* __restrict__ t_out,
    __hip_bfloat16* __restrict__ t_fc, __hip_bfloat16* __restrict__ t_proj,
    const float* __restrict__ x, const float* __restrict__ g,
    const float* __restrict__ bb, __hip_bfloat16* __restrict__ ln1o) {
  __shared__ float tl[64][65];
  const int id = blockIdx.x;
  const int t = threadIdx.x;
  if (id < 3072) {
    const float* in;
    __hip_bfloat16* out;
    int K, N, bx, by;
    if (id < 768) {
      in = w_qkv; out = t_qkv; K = 1024; N = 3072; bx = id % 48; by = id / 48;
    } else if (id < 1024) {
      const int i = id - 768;
      in = w_out; out = t_out; K = 1024; N = 1024; bx = i % 16; by = i / 16;
    } else if (id < 2048) {
      const int i = id - 1024;
      in = w_fc; out = t_fc; K = 1024; N = 4096; bx = i % 64; by = i / 64;
    } else {
      const int i = id - 2048;
      in = w_proj; out = t_proj; K = 4096; N = 1024; bx = i % 16; by = i / 16;
    }
    const int n0 = bx * 64, k0 = by * 64;
    const int rr = t >> 4;        // 0..15
    const int cc = (t & 15) * 4;  // 0..60
#pragma unroll
    for (int i = 0; i < 4; ++i) {
      const int row = rr + i * 16;
      const float4 v = *reinterpret_cast<const float4*>(&in[(size_t)(k0 + row) * N + n0 + cc]);
      tl[row][cc] = v.x; tl[row][cc + 1] = v.y; tl[row][cc + 2] = v.z; tl[row][cc + 3] = v.w;
    }
    __syncthreads();
#pragma unroll
    for (int i = 0; i < 4; ++i) {
      const int row = rr + i * 16;  // output row (n)
      ushort4 pk;
      pk.x = f2bfbits(tl[cc + 0][row]);
      pk.y = f2bfbits(tl[cc + 1][row]);
      pk.z = f2bfbits(tl[cc + 2][row]);
      pk.w = f2bfbits(tl[cc + 3][row]);
      *reinterpret_cast<ushort4*>(&out[(size_t)(n0 + row) * K + k0 + cc]) = pk;
    }
  } else {
    // LN1
    const int lane = t & 63;
    const int row = (id - 3072) * 4 + (t >> 6);
    const float* xr = x + (size_t)row * E_DIM;
    float4 v[4];
    float s = 0.f, s2 = 0.f;
#pragma unroll
    for (int i = 0; i < 4; ++i) {
      v[i] = *reinterpret_cast<const float4*>(&xr[(i * 64 + lane) * 4]);
      s  += v[i].x + v[i].y + v[i].z + v[i].w;
      s2 += v[i].x * v[i].x + v[i].y * v[i].y + v[i].z * v[i].z + v[i].w * v[i].w;
    }
#pragma unroll
    for (int m = 1; m < 64; m <<= 1) { s += __shfl_xor(s, m); s2 += __shfl_xor(s2, m); }
    const float mu = s * (1.0f / E_DIM);
    const float var = s2 * (1.0f / E_DIM) - mu * mu;
    const float rstd = rsqrtf(var + 1e-5f);
    __hip_bfloat16* orow = ln1o + (size_t)row * E_DIM;
#pragma unroll
    for (int i = 0; i < 4; ++i) {
      const int col = (i * 64 + lane) * 4;
      const float4 gv = *reinterpret_cast<const float4*>(&g[col]);
      const float4 bv = *reinterpret_cast<const float4*>(&bb[col]);
      ushort4 pk;
      pk.x = f2bfbits((v[i].x - mu) * rstd * gv.x + bv.x);
      pk.y = f2bfbits((v[i].y - mu) * rstd * gv.y + bv.y);
      pk.z = f2bfbits((v[i].z - mu) * rstd * gv.z + bv.z);
      pk.w = f2bfbits((v[i].w - mu) * rstd * gv.w + bv.w);
      *reinterpret_cast<ushort4*>(&orow[col]) = pk;
    }
  }
}

// ---------------- LayerNorm rows of 1024, f32 in -> bf16 out (LN2) ----------------
__global__ __launch_bounds__(256) void layernorm_bf16(
    const float* __restrict__ x, const float* __restrict__ g, const float* __restrict__ bb,
    __hip_bfloat16* __restrict__ out) {
  const int lane = threadIdx.x & 63;
  const int row = blockIdx.x * 4 + (threadIdx.x >> 6);
  const float* xr = x + (size_t)row * E_DIM;
  float4 v[4];
  float s = 0.f, s2 = 0.f;
#pragma unroll
  for (int i = 0; i < 4; ++i) {
    v[i] = *reinterpret_cast<const float4*>(&xr[(i * 64 + lane) * 4]);
    s  += v[i].x + v[i].y + v[i].z + v[i].w;
    s2 += v[i].x * v[i].x + v[i].y * v[i].y + v[i].z * v[i].z + v[i].w * v[i].w;
  }
#pragma unroll
  for (int m = 1; m < 64; m <<= 1) { s += __shfl_xor(s, m); s2 += __shfl_xor(s2, m); }
  const float mu = s * (1.0f / E_DIM);
  const float var = s2 * (1.0f / E_DIM) - mu * mu;
  const float rstd = rsqrtf(var + 1e-5f);
  __hip_bfloat16* orow = out + (size_t)row * E_DIM;
#pragma unroll
  for (int i = 0; i < 4; ++i) {
    const int col = (i * 64 + lane) * 4;
    const float4 gv = *reinterpret_cast<const float4*>(&g[col]);
    const float4 bv = *reinterpret_cast<const float4*>(&bb[col]);
    ushort4 pk;
    pk.x = f2bfbits((v[i].x - mu) * rstd * gv.x + bv.x);
    pk.y = f2bfbits((v[i].y - mu) * rstd * gv.y + bv.y);
    pk.z = f2bfbits((v[i].z - mu) * rstd * gv.z + bv.z);
    pk.w = f2bfbits((v[i].w - mu) * rstd * gv.w + bv.w);
    *reinterpret_cast<ushort4*>(&orow[col]) = pk;
  }
}

// ---------------- 128^2 bf16 GEMM, T2-swizzled LDS, 3 waves/EU ----------------
// launch_bounds (256,3): caps VGPR ~170 so 3 blocks/CU (12 waves) fit; actual
// usage ~140 -> no spill (watch FETCH_SIZE for the spill signature).
template <int GELU_ACT, int ADD_RES, int OUT_F32, int SCALE_Q>
__global__ __launch_bounds__(256, 3) void gemm_bt(
    const __hip_bfloat16* __restrict__ A, const __hip_bfloat16* __restrict__ Bt,
    const float* __restrict__ bias, const float* __restrict__ res,
    float* __restrict__ outF, __hip_bfloat16* __restrict__ outB,
    int M, int N, int K) {
  __shared__ __hip_bfloat16 sA[2][128 * 32];
  __shared__ __hip_bfloat16 sB[2][128 * 32];
  const int tid = threadIdx.x;
  const int w = tid >> 6, l = tid & 63;
  const int lhi = l >> 4, llo = l & 15;
  const int gx = gridDim.x;
  int wg = blockIdx.y * gx + blockIdx.x;
  const int cpx = (gx * gridDim.y) >> 3;
  wg = (wg & 7) * cpx + (wg >> 3);
  const int m0 = (wg / gx) * 128, n0 = (wg % gx) * 128;
  const int wr = (w >> 1) * 64, wc = (w & 1) * 64;
  f32x4 acc[4][4];
#pragma unroll
  for (int i = 0; i < 4; ++i)
#pragma unroll
    for (int j = 0; j < 4; ++j) acc[i][j] = zero4();

  const int nt = K >> 5;
  const int cswz = (((tid & 3) ^ ((tid >> 2) & 3)) << 3);
  auto stage = [&](int buf, int t) {
    const int k0 = t << 5;
#pragma unroll
    for (int i = 0; i < 2; ++i) {
      const int r = i * 64 + (tid >> 2);
      const int e = i * 2048 + tid * 8;
      __builtin_amdgcn_global_load_lds(
          (const __attribute__((address_space(1))) void*)(A + (size_t)(m0 + r) * K + k0 + cswz),
          (__attribute__((address_space(3))) void*)(&sA[buf][e]), 16, 0, 0);
      __builtin_amdgcn_global_load_lds(
          (const __attribute__((address_space(1))) void*)(Bt + (size_t)(n0 + r) * K + k0 + cswz),
          (__attribute__((address_space(3))) void*)(&sB[buf][e]), 16, 0, 0);
    }
  };

  stage(0, 0);
  for (int t = 0; t < nt; ++t) {
    const int cur = t & 1;
    __syncthreads();
    if (t + 1 < nt) stage(cur ^ 1, t + 1);
    const __hip_bfloat16* pa = sA[cur];
    const __hip_bfloat16* pb = sB[cur];
    short8 af[4], bfr[4];
    const int gsw = (lhi ^ (llo & 3)) << 3;
#pragma unroll
    for (int i = 0; i < 4; ++i) {
      af[i]  = *reinterpret_cast<const short8*>(pa + (wr + i * 16 + llo) * 32 + gsw);
      bfr[i] = *reinterpret_cast<const short8*>(pb + (wc + i * 16 + llo) * 32 + gsw);
    }
#pragma unroll
    for (int mi = 0; mi < 4; ++mi)
#pragma unroll
      for (int ni = 0; ni < 4; ++ni)
        acc[mi][ni] = __builtin_amdgcn_mfma_f32_16x16x32_bf16(af[mi], bfr[ni], acc[mi][ni], 0, 0, 0);
  }

#pragma unroll
  for (int mi = 0; mi < 4; ++mi) {
#pragma unroll
    for (int ni = 0; ni < 4; ++ni) {
      const int row = m0 + wr + mi * 16 + lhi * 4;
      const int col = n0 + wc + ni * 16 + llo;
      const float bc = bias[col];
      float qs = 1.0f;
      if (SCALE_Q) qs = ((col % 192) < 64) ? 0.125f : 1.0f;
#pragma unroll
      for (int j = 0; j < 4; ++j) {
        float v = acc[mi][ni][j] + bc;
        if (SCALE_Q) v *= qs;
        if (GELU_ACT) v = gelu_tanh(v);
        if (ADD_RES) v += res[(size_t)(row + j) * N + col];
        if (OUT_F32) outF[(size_t)(row + j) * N + col] = v;
        else outB[(size_t)(row + j) * N + col] = __float2bfloat16(v);
      }
    }
  }
}

// ---------------- V transpose: qkv V-region -> vt[b][h][d][T] ----------------
__global__ __launch_bounds__(256) void transpose_v(
    const __hip_bfloat16* __restrict__ qkv, __hip_bfloat16* __restrict__ vt) {
  const int t0 = blockIdx.x * 64, h = blockIdx.y, b = blockIdx.z;
  const size_t rb = (size_t)b * T_DIM;
  const size_t obase = ((size_t)(b * NH + h) * 64) * T_DIM;
  __shared__ unsigned short tl[64][64];
  const int tid = threadIdx.x;
#pragma unroll
  for (int k = 0; k < 2; ++k) {
    const int e = k * 2048 + tid * 8;
    const int tr = e >> 6, dc = e & 63;
    const short8 v =
        *reinterpret_cast<const short8*>(qkv + (rb + t0 + tr) * 3072 + h * 192 + 128 + dc);
    *reinterpret_cast<short8*>(&tl[tr][dc ^ ((tr & 7) << 3)]) = v;
  }
  __syncthreads();
#pragma unroll
  for (int k = 0; k < 2; ++k) {
    const int e = k * 2048 + tid * 8;
    const int dr = e >> 6, tc = e & 63;
    short8 o;
#pragma unroll
    for (int jj = 0; jj < 8; ++jj)
      o[jj] = (short)tl[tc + jj][dr ^ (((tc + jj) & 7) << 3)];
    *reinterpret_cast<short8*>(&vt[obase + (size_t)dr * T_DIM + t0 + tc]) = o;
  }
}

// ---------------- causal flash attention v6 (round-10 version, defer-max reverted) --
__global__ __launch_bounds__(256) void attn_fwd(
    const __hip_bfloat16* __restrict__ qkv, const __hip_bfloat16* __restrict__ vt,
    __hip_bfloat16* __restrict__ aout) {
  const int hb = blockIdx.x;
  const int h = hb & 15, b = hb >> 4;
  const int tid = threadIdx.x, w = tid >> 6, l = tid & 63;
  const int lhi = l >> 4, llo = l & 15;
  const int pr = w >> 1;               // pair slot in block (0,1)
  const int s = w & 1;                 // kv half
  const int p = blockIdx.y * 2 + pr;   // pair index 0..31
  const size_t rb = (size_t)b * T_DIM;
  const size_t vbase = ((size_t)(b * NH + h) * 64) * T_DIM;
  __shared__ __hip_bfloat16 sP[4][32][72];
  __shared__ float mrg[2][64][49];  // [pair][lane][32 O + 8 m + 8 l + pad]

  short8 onesb;
#pragma unroll
  for (int i = 0; i < 8; ++i) onesb[i] = (short)0x3F80;  // bf16 1.0

#pragma unroll
  for (int half = 0; half < 2; ++half) {
    const int tile = half ? (63 - p) : p;  // 32-row q tile, 0..63
    const int q0 = tile * 32;
    const int nkv = (tile >> 1) + 1;       // kv-tiles of 64
    const int base = (tile & 1) << 5;      // diag offset: 0 or 32
    const int kt_begin = s ? (nkv >> 1) : 0;
    const int kt_end   = s ? nkv : (nkv >> 1);

    short8 qf[2][2];
#pragma unroll
    for (int mf = 0; mf < 2; ++mf) {
      const __hip_bfloat16* qp =
          qkv + ((rb + q0 + mf * 16 + llo) * 3072 + h * 192 + lhi * 8);
      qf[mf][0] = *reinterpret_cast<const short8*>(qp);
      qf[mf][1] = *reinterpret_cast<const short8*>(qp + 32);
    }
    float mrun[2][4], lrun[2][4];
    f32x4 oacc[2][4];
#pragma unroll
    for (int mf = 0; mf < 2; ++mf)
#pragma unroll
      for (int j = 0; j < 4; ++j) { mrun[mf][j] = -1e30f; lrun[mf][j] = 0.f; }
#pragma unroll
    for (int mf = 0; mf < 2; ++mf)
#pragma unroll
      for (int di = 0; di < 4; ++di) oacc[mf][di] = zero4();

    auto loadK = [&](short8 (&dst)[4][2], int k0) {
#pragma unroll
      for (int ni = 0; ni < 4; ++ni) {
        const __hip_bfloat16* kp =
            qkv + ((rb + k0 + ni * 16 + llo) * 3072 + h * 192 + 64 + lhi * 8);
        dst[ni][0] = *reinterpret_cast<const short8*>(kp);
        dst[ni][1] = *reinterpret_cast<const short8*>(kp + 32);
      }
    };

    auto step = [&](short8 (&cK)[4][2], short8 (&nK)[4][2], int kt) {
      const bool diag = (kt == nkv - 1);
      const bool evendiag = diag && (base == 0);  // ni>=2 / k>=32 dead
      // S = Q K^T
      f32x4 sc[2][4];
      __builtin_amdgcn_s_setprio(1);
#pragma unroll
      for (int mf = 0; mf < 2; ++mf)
#pragma unroll
        for (int ni = 0; ni < 4; ++ni) {
          sc[mf][ni] = zero4();
          if (!evendiag || ni < 2) {
            sc[mf][ni] =
                __builtin_amdgcn_mfma_f32_16x16x32_bf16(qf[mf][0], cK[ni][0], sc[mf][ni], 0, 0, 0);
            sc[mf][ni] =
                __builtin_amdgcn_mfma_f32_16x16x32_bf16(qf[mf][1], cK[ni][1], sc[mf][ni], 0, 0, 0);
          }
        }
      __builtin_amdgcn_s_setprio(0);
      // prefetch next K tile
      if (kt + 1 < kt_end) loadK(nK, (kt + 1) * 64);
      // V for THIS step (L2 latency hides under softmax)
      short8 vCur[4][2];
#pragma unroll
      for (int di = 0; di < 4; ++di) {
        const __hip_bfloat16* vp =
            vt + (vbase + (size_t)(di * 16 + llo) * T_DIM + kt * 64 + lhi * 8);
        vCur[di][0] = *reinterpret_cast<const short8*>(vp);
        vCur[di][1] = *reinterpret_cast<const short8*>(vp + 32);
      }
      // online softmax
      float corr[2][4];
#pragma unroll
      for (int mf = 0; mf < 2; ++mf)
#pragma unroll
        for (int j = 0; j < 4; ++j) {
          const int ql = mf * 16 + lhi * 4 + j;
          float sv[4];
#pragma unroll
          for (int ni = 0; ni < 4; ++ni) {
            float sval = sc[mf][ni][j];
            if (diag) sval = (ni * 16 + llo <= base + ql) ? sval : -1e30f;
            sv[ni] = sval;
          }
          float mx = fmaxf(fmaxf(sv[0], sv[1]), fmaxf(sv[2], sv[3]));
#pragma unroll
          for (int d = 1; d < 16; d <<= 1) mx = fmaxf(mx, __shfl_xor(mx, d));
          const float mnew = fmaxf(mrun[mf][j], mx);
          const float c = __expf(mrun[mf][j] - mnew);
          mrun[mf][j] = mnew;
          corr[mf][j] = c;
#pragma unroll
          for (int ni = 0; ni < 4; ++ni)
            sP[w][mf * 16 + lhi * 4 + j][ni * 16 + llo] = __float2bfloat16(__expf(sv[ni] - mnew));
#pragma unroll
          for (int di = 0; di < 4; ++di) oacc[mf][di][j] *= c;
        }
      asm volatile("s_waitcnt lgkmcnt(0)" ::: "memory");
      // O += P V ; l += P 1
      __builtin_amdgcn_s_setprio(1);
#pragma unroll
      for (int mf = 0; mf < 2; ++mf) {
        const short8 pf0 = *reinterpret_cast<const short8*>(&sP[w][mf * 16 + llo][lhi * 8]);
        const short8 pf1 = *reinterpret_cast<const short8*>(&sP[w][mf * 16 + llo][32 + lhi * 8]);
        f32x4 lacc = zero4();
        lacc = __builtin_amdgcn_mfma_f32_16x16x32_bf16(pf0, onesb, lacc, 0, 0, 0);
        if (!evendiag)
          lacc = __builtin_amdgcn_mfma_f32_16x16x32_bf16(pf1, onesb, lacc, 0, 0, 0);
#pragma unroll
        for (int di = 0; di < 4; ++di) {
          oacc[mf][di] =
              __builtin_amdgcn_mfma_f32_16x16x32_bf16(pf0, vCur[di][0], oacc[mf][di], 0, 0, 0);
          if (!evendiag)
            oacc[mf][di] =
                __builtin_amdgcn_mfma_f32_16x16x32_bf16(pf1, vCur[di][1], oacc[mf][di], 0, 0, 0);
        }
#pragma unroll
        for (int j = 0; j < 4; ++j)
          lrun[mf][j] = lrun[mf][j] * corr[mf][j] + lacc[j];
      }
      __builtin_amdgcn_s_setprio(0);
    };

    short8 kA[4][2], kB[4][2];
    if (kt_begin < kt_end) loadK(kA, kt_begin * 64);
    for (int kt = kt_begin; kt < kt_end; ++kt) {
      if ((kt - kt_begin) & 1) step(kB, kA, kt);
      else                     step(kA, kB, kt);
    }

    // ---- merge the two kv-halves (flash-decoding combine) ----
    if (s == 0) {
      float* dst = &mrg[pr][l][0];
#pragma unroll
      for (int mf = 0; mf < 2; ++mf)
#pragma unroll
        for (int di = 0; di < 4; ++di)
#pragma unroll
          for (int j = 0; j < 4; ++j) dst[(mf * 4 + di) * 4 + j] = oacc[mf][di][j];
#pragma unroll
      for (int mf = 0; mf < 2; ++mf)
#pragma unroll
        for (int j = 0; j < 4; ++j) {
          dst[32 + mf * 4 + j] = mrun[mf][j];
          dst[40 + mf * 4 + j] = lrun[mf][j];
        }
    }
    __syncthreads();
    if (s == 1) {
      const float* src = &mrg[pr][l][0];
#pragma unroll
      for (int mf = 0; mf < 2; ++mf)
#pragma unroll
        for (int j = 0; j < 4; ++j) {
          const float m0 = src[32 + mf * 4 + j], l0 = src[40 + mf * 4 + j];
          const float m1 = mrun[mf][j], l1 = lrun[mf][j];
          const float mm = fmaxf(m0, m1);
          const float a0 = __expf(m0 - mm), a1 = __expf(m1 - mm);
          const float linv = 1.0f / (l0 * a0 + l1 * a1);
          const size_t row = rb + q0 + mf * 16 + lhi * 4 + j;
#pragma unroll
          for (int di = 0; di < 4; ++di) {
            const float o = (src[(mf * 4 + di) * 4 + j] * a0 + oacc[mf][di][j] * a1) * linv;
            aout[row * 1024 + h * 64 + di * 16 + llo] = __float2bfloat16(o);
          }
        }
    }
    __syncthreads();
  }
}

// ---------------- launch ----------------
extern "C" void kernel_launch(void* const* d_in, const int* in_sizes, int n_in,
                              void* d_out, int out_size, void* d_ws, size_t ws_size,
                              hipStream_t stream) {
  (void)in_sizes; (void)n_in; (void)out_size; (void)ws_size;
  const float* x      = (const float*)d_in[0];
  const float* ln1_g  = (const float*)d_in[1];
  const float* ln1_b  = (const float*)d_in[2];
  const float* w_qkv  = (const float*)d_in[3];
  const float* b_qkv  = (const float*)d_in[4];
  const float* w_out  = (const float*)d_in[5];
  const float* b_out  = (const float*)d_in[6];
  const float* ln2_g  = (const float*)d_in[7];
  const float* ln2_b  = (const float*)d_in[8];
  const float* w_fc   = (const float*)d_in[9];
  const float* b_fc   = (const float*)d_in[10];
  const float* w_proj = (const float*)d_in[11];
  const float* b_proj = (const float*)d_in[12];
  float* out = (float*)d_out;

  const int M = 2 * T_DIM;  // 4096 rows
  char* wsp = (char*)d_ws;
  size_t off = 0;
  auto carve = [&](size_t bytes) {
    void* p = wsp + off;
    off += (bytes + 255) & ~(size_t)255;
    return p;
  };
  __hip_bfloat16* wt_qkv  = (__hip_bfloat16*)carve((size_t)3072 * 1024 * 2);
  __hip_bfloat16* wt_out  = (__hip_bfloat16*)carve((size_t)1024 * 1024 * 2);
  __hip_bfloat16* wt_fc   = (__hip_bfloat16*)carve((size_t)4096 * 1024 * 2);
  __hip_bfloat16* wt_proj = (__hip_bfloat16*)carve((size_t)1024 * 4096 * 2);
  __hip_bfloat16* ln1o    = (__hip_bfloat16*)carve((size_t)M * 1024 * 2);
  __hip_bfloat16* qkvb    = (__hip_bfloat16*)carve((size_t)M * 3072 * 2);
  __hip_bfloat16* vtb     = (__hip_bfloat16*)carve((size_t)2 * NH * 64 * T_DIM * 2);
  __hip_bfloat16* attnb   = (__hip_bfloat16*)carve((size_t)M * 1024 * 2);
  float*          x2      = (float*)carve((size_t)M * 1024 * 4);
  __hip_bfloat16* h1      = (__hip_bfloat16*)carve((size_t)M * 4096 * 2);
  __hip_bfloat16* ln2o    = ln1o;  // ln1 output dead after QKV GEMM; reuse

  // fused prologue: 4 weight transposes + LN1 in one launch
  prep<<<4096, 256, 0, stream>>>(w_qkv, w_out, w_fc, w_proj,
                                 wt_qkv, wt_out, wt_fc, wt_proj,
                                 x, ln1_g, ln1_b, ln1o);
  gemm_bt<0, 0, 0, 1><<<dim3(3072 / 128, M / 128), 256, 0, stream>>>(
      ln1o, wt_qkv, b_qkv, nullptr, nullptr, qkvb, M, 3072, 1024);
  transpose_v<<<dim3(T_DIM / 64, NH, 2), 256, 0, stream>>>(qkvb, vtb);
  attn_fwd<<<dim3(32, 16), 256, 0, stream>>>(qkvb, vtb, attnb);
  gemm_bt<0, 1, 1, 0><<<dim3(1024 / 128, M / 128), 256, 0, stream>>>(
      attnb, wt_out, b_out, x, x2, nullptr, M, 1024, 1024);
  layernorm_bf16<<<M / 4, 256, 0, stream>>>(x2, ln2_g, ln2_b, ln2o);
  gemm_bt<1, 0, 0, 0><<<dim3(4096 / 128, M / 128), 256, 0, stream>>>(
      ln2o, wt_fc, b_fc, nullptr, nullptr, h1, M, 4096, 1024);
  gemm_bt<0, 1, 1, 0><<<dim3(1024 / 128, M / 128), 256, 0, stream>>>(
      h1, wt_proj, b_proj, x2, out, nullptr, M, 1024, 4096);
}

// Round 16
// 296.340 us; speedup vs baseline: 1.2806x; 1.0598x over previous
//
#include <hip/hip_runtime.h>
#include <hip/hip_bf16.h>

// Transformer block forward: B=2, T=2048, E=1024, H=16, D=64.
// Pipeline: prep (transposes+LN1) | QKV GEMM (128^2 swz) | V transpose |
//           flash attn v6 | out-proj+res (64x128 swz) | LN2 | FC+GELU (128^2) |
//           proj+res (64x128).  N=1024 GEMMs use 64x128 tiles: 512 blocks
//           = 2 blocks/CU (vs 256 = 1/CU) for latency hiding.

#define T_DIM 2048
#define E_DIM 1024
#define NH 16

using short8 = __attribute__((__ext_vector_type__(8))) short;
using f32x4  = __attribute__((__ext_vector_type__(4))) float;

static __device__ __forceinline__ f32x4 zero4() {
  f32x4 z = {0.f, 0.f, 0.f, 0.f};
  return z;
}

static __device__ __forceinline__ unsigned short f2bfbits(float f) {
  __hip_bfloat16 h = __float2bfloat16(f);
  return *reinterpret_cast<unsigned short*>(&h);
}

static __device__ __forceinline__ float gelu_tanh(float x) {
  float z = 0.7978845608028654f * (x + 0.044715f * x * x * x);
  float e = __expf(2.0f * z);
  float th = 1.0f - 2.0f / (e + 1.0f);
  return 0.5f * x * (1.0f + th);
}

// ---------------- prep: 4 weight transposes (f32 [K][N] -> bf16 [N][K]) + LN1 ----
__global__ __launch_bounds__(256) void prep(
    const float* __restrict__ w_qkv, const float* __restrict__ w_out,
    const float* __restrict__ w_fc, const float* __restrict__ w_proj,
    __hip_bfloat16* __restrict__ t_qkv, __hip_bfloat16* __restrict__ t_out,
    __hip_bfloat16* __restrict__ t_fc, __hip_bfloat16* __restrict__ t_proj,
    const float* __restrict__ x, const float* __restrict__ g,
    const float* __restrict__ bb, __hip_bfloat16* __restrict__ ln1o) {
  __shared__ float tl[64][65];
  const int id = blockIdx.x;
  const int t = threadIdx.x;
  if (id < 3072) {
    const float* in;
    __hip_bfloat16* out;
    int K, N, bx, by;
    if (id < 768) {
      in = w_qkv; out = t_qkv; K = 1024; N = 3072; bx = id % 48; by = id / 48;
    } else if (id < 1024) {
      const int i = id - 768;
      in = w_out; out = t_out; K = 1024; N = 1024; bx = i % 16; by = i / 16;
    } else if (id < 2048) {
      const int i = id - 1024;
      in = w_fc; out = t_fc; K = 1024; N = 4096; bx = i % 64; by = i / 64;
    } else {
      const int i = id - 2048;
      in = w_proj; out = t_proj; K = 4096; N = 1024; bx = i % 16; by = i / 16;
    }
    const int n0 = bx * 64, k0 = by * 64;
    const int rr = t >> 4;        // 0..15
    const int cc = (t & 15) * 4;  // 0..60
#pragma unroll
    for (int i = 0; i < 4; ++i) {
      const int row = rr + i * 16;
      const float4 v = *reinterpret_cast<const float4*>(&in[(size_t)(k0 + row) * N + n0 + cc]);
      tl[row][cc] = v.x; tl[row][cc + 1] = v.y; tl[row][cc + 2] = v.z; tl[row][cc + 3] = v.w;
    }
    __syncthreads();
#pragma unroll
    for (int i = 0; i < 4; ++i) {
      const int row = rr + i * 16;  // output row (n)
      ushort4 pk;
      pk.x = f2bfbits(tl[cc + 0][row]);
      pk.y = f2bfbits(tl[cc + 1][row]);
      pk.z = f2bfbits(tl[cc + 2][row]);
      pk.w = f2bfbits(tl[cc + 3][row]);
      *reinterpret_cast<ushort4*>(&out[(size_t)(n0 + row) * K + k0 + cc]) = pk;
    }
  } else {
    // LN1
    const int lane = t & 63;
    const int row = (id - 3072) * 4 + (t >> 6);
    const float* xr = x + (size_t)row * E_DIM;
    float4 v[4];
    float s = 0.f, s2 = 0.f;
#pragma unroll
    for (int i = 0; i < 4; ++i) {
      v[i] = *reinterpret_cast<const float4*>(&xr[(i * 64 + lane) * 4]);
      s  += v[i].x + v[i].y + v[i].z + v[i].w;
      s2 += v[i].x * v[i].x + v[i].y * v[i].y + v[i].z * v[i].z + v[i].w * v[i].w;
    }
#pragma unroll
    for (int m = 1; m < 64; m <<= 1) { s += __shfl_xor(s, m); s2 += __shfl_xor(s2, m); }
    const float mu = s * (1.0f / E_DIM);
    const float var = s2 * (1.0f / E_DIM) - mu * mu;
    const float rstd = rsqrtf(var + 1e-5f);
    __hip_bfloat16* orow = ln1o + (size_t)row * E_DIM;
#pragma unroll
    for (int i = 0; i < 4; ++i) {
      const int col = (i * 64 + lane) * 4;
      const float4 gv = *reinterpret_cast<const float4*>(&g[col]);
      const float4 bv = *reinterpret_cast<const float4*>(&bb[col]);
      ushort4 pk;
      pk.x = f2bfbits((v[i].x - mu) * rstd * gv.x + bv.x);
      pk.y = f2bfbits((v[i].y - mu) * rstd * gv.y + bv.y);
      pk.z = f2bfbits((v[i].z - mu) * rstd * gv.z + bv.z);
      pk.w = f2bfbits((v[i].w - mu) * rstd * gv.w + bv.w);
      *reinterpret_cast<ushort4*>(&orow[col]) = pk;
    }
  }
}

// ---------------- LayerNorm rows of 1024, f32 in -> bf16 out (LN2) ----------------
__global__ __launch_bounds__(256) void layernorm_bf16(
    const float* __restrict__ x, const float* __restrict__ g, const float* __restrict__ bb,
    __hip_bfloat16* __restrict__ out) {
  const int lane = threadIdx.x & 63;
  const int row = blockIdx.x * 4 + (threadIdx.x >> 6);
  const float* xr = x + (size_t)row * E_DIM;
  float4 v[4];
  float s = 0.f, s2 = 0.f;
#pragma unroll
  for (int i = 0; i < 4; ++i) {
    v[i] = *reinterpret_cast<const float4*>(&xr[(i * 64 + lane) * 4]);
    s  += v[i].x + v[i].y + v[i].z + v[i].w;
    s2 += v[i].x * v[i].x + v[i].y * v[i].y + v[i].z * v[i].z + v[i].w * v[i].w;
  }
#pragma unroll
  for (int m = 1; m < 64; m <<= 1) { s += __shfl_xor(s, m); s2 += __shfl_xor(s2, m); }
  const float mu = s * (1.0f / E_DIM);
  const float var = s2 * (1.0f / E_DIM) - mu * mu;
  const float rstd = rsqrtf(var + 1e-5f);
  __hip_bfloat16* orow = out + (size_t)row * E_DIM;
#pragma unroll
  for (int i = 0; i < 4; ++i) {
    const int col = (i * 64 + lane) * 4;
    const float4 gv = *reinterpret_cast<const float4*>(&g[col]);
    const float4 bv = *reinterpret_cast<const float4*>(&bb[col]);
    ushort4 pk;
    pk.x = f2bfbits((v[i].x - mu) * rstd * gv.x + bv.x);
    pk.y = f2bfbits((v[i].y - mu) * rstd * gv.y + bv.y);
    pk.z = f2bfbits((v[i].z - mu) * rstd * gv.z + bv.z);
    pk.w = f2bfbits((v[i].w - mu) * rstd * gv.w + bv.w);
    *reinterpret_cast<ushort4*>(&orow[col]) = pk;
  }
}

// ---------------- 128^2 bf16 GEMM, T2-swizzled LDS, 3 waves/EU ----------------
template <int GELU_ACT, int ADD_RES, int OUT_F32, int SCALE_Q>
__global__ __launch_bounds__(256, 3) void gemm_bt(
    const __hip_bfloat16* __restrict__ A, const __hip_bfloat16* __restrict__ Bt,
    const float* __restrict__ bias, const float* __restrict__ res,
    float* __restrict__ outF, __hip_bfloat16* __restrict__ outB,
    int M, int N, int K) {
  __shared__ __hip_bfloat16 sA[2][128 * 32];
  __shared__ __hip_bfloat16 sB[2][128 * 32];
  const int tid = threadIdx.x;
  const int w = tid >> 6, l = tid & 63;
  const int lhi = l >> 4, llo = l & 15;
  const int gx = gridDim.x;
  int wg = blockIdx.y * gx + blockIdx.x;
  const int cpx = (gx * gridDim.y) >> 3;
  wg = (wg & 7) * cpx + (wg >> 3);
  const int m0 = (wg / gx) * 128, n0 = (wg % gx) * 128;
  const int wr = (w >> 1) * 64, wc = (w & 1) * 64;
  f32x4 acc[4][4];
#pragma unroll
  for (int i = 0; i < 4; ++i)
#pragma unroll
    for (int j = 0; j < 4; ++j) acc[i][j] = zero4();

  const int nt = K >> 5;
  const int cswz = (((tid & 3) ^ ((tid >> 2) & 3)) << 3);
  auto stage = [&](int buf, int t) {
    const int k0 = t << 5;
#pragma unroll
    for (int i = 0; i < 2; ++i) {
      const int r = i * 64 + (tid >> 2);
      const int e = i * 2048 + tid * 8;
      __builtin_amdgcn_global_load_lds(
          (const __attribute__((address_space(1))) void*)(A + (size_t)(m0 + r) * K + k0 + cswz),
          (__attribute__((address_space(3))) void*)(&sA[buf][e]), 16, 0, 0);
      __builtin_amdgcn_global_load_lds(
          (const __attribute__((address_space(1))) void*)(Bt + (size_t)(n0 + r) * K + k0 + cswz),
          (__attribute__((address_space(3))) void*)(&sB[buf][e]), 16, 0, 0);
    }
  };

  stage(0, 0);
  for (int t = 0; t < nt; ++t) {
    const int cur = t & 1;
    __syncthreads();
    if (t + 1 < nt) stage(cur ^ 1, t + 1);
    const __hip_bfloat16* pa = sA[cur];
    const __hip_bfloat16* pb = sB[cur];
    short8 af[4], bfr[4];
    const int gsw = (lhi ^ (llo & 3)) << 3;
#pragma unroll
    for (int i = 0; i < 4; ++i) {
      af[i]  = *reinterpret_cast<const short8*>(pa + (wr + i * 16 + llo) * 32 + gsw);
      bfr[i] = *reinterpret_cast<const short8*>(pb + (wc + i * 16 + llo) * 32 + gsw);
    }
#pragma unroll
    for (int mi = 0; mi < 4; ++mi)
#pragma unroll
      for (int ni = 0; ni < 4; ++ni)
        acc[mi][ni] = __builtin_amdgcn_mfma_f32_16x16x32_bf16(af[mi], bfr[ni], acc[mi][ni], 0, 0, 0);
  }

#pragma unroll
  for (int mi = 0; mi < 4; ++mi) {
#pragma unroll
    for (int ni = 0; ni < 4; ++ni) {
      const int row = m0 + wr + mi * 16 + lhi * 4;
      const int col = n0 + wc + ni * 16 + llo;
      const float bc = bias[col];
      float qs = 1.0f;
      if (SCALE_Q) qs = ((col % 192) < 64) ? 0.125f : 1.0f;
#pragma unroll
      for (int j = 0; j < 4; ++j) {
        float v = acc[mi][ni][j] + bc;
        if (SCALE_Q) v *= qs;
        if (GELU_ACT) v = gelu_tanh(v);
        if (ADD_RES) v += res[(size_t)(row + j) * N + col];
        if (OUT_F32) outF[(size_t)(row + j) * N + col] = v;
        else outB[(size_t)(row + j) * N + col] = __float2bfloat16(v);
      }
    }
  }
}

// ---------------- 64x128 bf16 GEMM for N=1024 outputs (occupancy variant) ----
// BM=64, BN=128, BK=32; 4 waves each 32x64 (2x4 frags). Grid (N/128, M/64) =
// 512 blocks = 2 blocks/CU -> 2 waves/SIMD (vs 1 at 128^2 with 256 blocks).
template <int ADD_RES, int OUT_F32>
__global__ __launch_bounds__(256, 3) void gemm_small(
    const __hip_bfloat16* __restrict__ A, const __hip_bfloat16* __restrict__ Bt,
    const float* __restrict__ bias, const float* __restrict__ res,
    float* __restrict__ outF, __hip_bfloat16* __restrict__ outB,
    int M, int N, int K) {
  __shared__ __hip_bfloat16 sA[2][64 * 32];
  __shared__ __hip_bfloat16 sB[2][128 * 32];
  const int tid = threadIdx.x;
  const int w = tid >> 6, l = tid & 63;
  const int lhi = l >> 4, llo = l & 15;
  const int gx = gridDim.x;
  int wg = blockIdx.y * gx + blockIdx.x;
  const int cpx = (gx * gridDim.y) >> 3;
  wg = (wg & 7) * cpx + (wg >> 3);
  const int m0 = (wg / gx) * 64, n0 = (wg % gx) * 128;
  const int wr = (w >> 1) * 32, wc = (w & 1) * 64;
  f32x4 acc[2][4];
#pragma unroll
  for (int i = 0; i < 2; ++i)
#pragma unroll
    for (int j = 0; j < 4; ++j) acc[i][j] = zero4();

  const int nt = K >> 5;
  const int cswz = (((tid & 3) ^ ((tid >> 2) & 3)) << 3);
  auto stage = [&](int buf, int t) {
    const int k0 = t << 5;
    {  // A: 64 rows, 1 load/thread
      const int r = tid >> 2;
      const int e = tid * 8;
      __builtin_amdgcn_global_load_lds(
          (const __attribute__((address_space(1))) void*)(A + (size_t)(m0 + r) * K + k0 + cswz),
          (__attribute__((address_space(3))) void*)(&sA[buf][e]), 16, 0, 0);
    }
#pragma unroll
    for (int i = 0; i < 2; ++i) {  // B: 128 rows, 2 loads/thread
      const int r = i * 64 + (tid >> 2);
      const int e = i * 2048 + tid * 8;
      __builtin_amdgcn_global_load_lds(
          (const __attribute__((address_space(1))) void*)(Bt + (size_t)(n0 + r) * K + k0 + cswz),
          (__attribute__((address_space(3))) void*)(&sB[buf][e]), 16, 0, 0);
    }
  };

  stage(0, 0);
  for (int t = 0; t < nt; ++t) {
    const int cur = t & 1;
    __syncthreads();
    if (t + 1 < nt) stage(cur ^ 1, t + 1);
    const __hip_bfloat16* pa = sA[cur];
    const __hip_bfloat16* pb = sB[cur];
    short8 af[2], bfr[4];
    const int gsw = (lhi ^ (llo & 3)) << 3;
#pragma unroll
    for (int i = 0; i < 2; ++i)
      af[i] = *reinterpret_cast<const short8*>(pa + (wr + i * 16 + llo) * 32 + gsw);
#pragma unroll
    for (int i = 0; i < 4; ++i)
      bfr[i] = *reinterpret_cast<const short8*>(pb + (wc + i * 16 + llo) * 32 + gsw);
#pragma unroll
    for (int mi = 0; mi < 2; ++mi)
#pragma unroll
      for (int ni = 0; ni < 4; ++ni)
        acc[mi][ni] = __builtin_amdgcn_mfma_f32_16x16x32_bf16(af[mi], bfr[ni], acc[mi][ni], 0, 0, 0);
  }

#pragma unroll
  for (int mi = 0; mi < 2; ++mi) {
#pragma unroll
    for (int ni = 0; ni < 4; ++ni) {
      const int row = m0 + wr + mi * 16 + lhi * 4;
      const int col = n0 + wc + ni * 16 + llo;
      const float bc = bias[col];
#pragma unroll
      for (int j = 0; j < 4; ++j) {
        float v = acc[mi][ni][j] + bc;
        if (ADD_RES) v += res[(size_t)(row + j) * N + col];
        if (OUT_F32) outF[(size_t)(row + j) * N + col] = v;
        else outB[(size_t)(row + j) * N + col] = __float2bfloat16(v);
      }
    }
  }
}

// ---------------- V transpose: qkv V-region -> vt[b][h][d][T] ----------------
__global__ __launch_bounds__(256) void transpose_v(
    const __hip_bfloat16* __restrict__ qkv, __hip_bfloat16* __restrict__ vt) {
  const int t0 = blockIdx.x * 64, h = blockIdx.y, b = blockIdx.z;
  const size_t rb = (size_t)b * T_DIM;
  const size_t obase = ((size_t)(b * NH + h) * 64) * T_DIM;
  __shared__ unsigned short tl[64][64];
  const int tid = threadIdx.x;
#pragma unroll
  for (int k = 0; k < 2; ++k) {
    const int e = k * 2048 + tid * 8;
    const int tr = e >> 6, dc = e & 63;
    const short8 v =
        *reinterpret_cast<const short8*>(qkv + (rb + t0 + tr) * 3072 + h * 192 + 128 + dc);
    *reinterpret_cast<short8*>(&tl[tr][dc ^ ((tr & 7) << 3)]) = v;
  }
  __syncthreads();
#pragma unroll
  for (int k = 0; k < 2; ++k) {
    const int e = k * 2048 + tid * 8;
    const int dr = e >> 6, tc = e & 63;
    short8 o;
#pragma unroll
    for (int jj = 0; jj < 8; ++jj)
      o[jj] = (short)tl[tc + jj][dr ^ (((tc + jj) & 7) << 3)];
    *reinterpret_cast<short8*>(&vt[obase + (size_t)dr * T_DIM + t0 + tc]) = o;
  }
}

// ---------------- causal flash attention v6 ----------------
__global__ __launch_bounds__(256) void attn_fwd(
    const __hip_bfloat16* __restrict__ qkv, const __hip_bfloat16* __restrict__ vt,
    __hip_bfloat16* __restrict__ aout) {
  const int hb = blockIdx.x;
  const int h = hb & 15, b = hb >> 4;
  const int tid = threadIdx.x, w = tid >> 6, l = tid & 63;
  const int lhi = l >> 4, llo = l & 15;
  const int pr = w >> 1;               // pair slot in block (0,1)
  const int s = w & 1;                 // kv half
  const int p = blockIdx.y * 2 + pr;   // pair index 0..31
  const size_t rb = (size_t)b * T_DIM;
  const size_t vbase = ((size_t)(b * NH + h) * 64) * T_DIM;
  __shared__ __hip_bfloat16 sP[4][32][72];
  __shared__ float mrg[2][64][49];  // [pair][lane][32 O + 8 m + 8 l + pad]

  short8 onesb;
#pragma unroll
  for (int i = 0; i < 8; ++i) onesb[i] = (short)0x3F80;  // bf16 1.0

#pragma unroll
  for (int half = 0; half < 2; ++half) {
    const int tile = half ? (63 - p) : p;  // 32-row q tile, 0..63
    const int q0 = tile * 32;
    const int nkv = (tile >> 1) + 1;       // kv-tiles of 64
    const int base = (tile & 1) << 5;      // diag offset: 0 or 32
    const int kt_begin = s ? (nkv >> 1) : 0;
    const int kt_end   = s ? nkv : (nkv >> 1);

    short8 qf[2][2];
#pragma unroll
    for (int mf = 0; mf < 2; ++mf) {
      const __hip_bfloat16* qp =
          qkv + ((rb + q0 + mf * 16 + llo) * 3072 + h * 192 + lhi * 8);
      qf[mf][0] = *reinterpret_cast<const short8*>(qp);
      qf[mf][1] = *reinterpret_cast<const short8*>(qp + 32);
    }
    float mrun[2][4], lrun[2][4];
    f32x4 oacc[2][4];
#pragma unroll
    for (int mf = 0; mf < 2; ++mf)
#pragma unroll
      for (int j = 0; j < 4; ++j) { mrun[mf][j] = -1e30f; lrun[mf][j] = 0.f; }
#pragma unroll
    for (int mf = 0; mf < 2; ++mf)
#pragma unroll
      for (int di = 0; di < 4; ++di) oacc[mf][di] = zero4();

    auto loadK = [&](short8 (&dst)[4][2], int k0) {
#pragma unroll
      for (int ni = 0; ni < 4; ++ni) {
        const __hip_bfloat16* kp =
            qkv + ((rb + k0 + ni * 16 + llo) * 3072 + h * 192 + 64 + lhi * 8);
        dst[ni][0] = *reinterpret_cast<const short8*>(kp);
        dst[ni][1] = *reinterpret_cast<const short8*>(kp + 32);
      }
    };

    auto step = [&](short8 (&cK)[4][2], short8 (&nK)[4][2], int kt) {
      const bool diag = (kt == nkv - 1);
      const bool evendiag = diag && (base == 0);  // ni>=2 / k>=32 dead
      // S = Q K^T
      f32x4 sc[2][4];
      __builtin_amdgcn_s_setprio(1);
#pragma unroll
      for (int mf = 0; mf < 2; ++mf)
#pragma unroll
        for (int ni = 0; ni < 4; ++ni) {
          sc[mf][ni] = zero4();
          if (!evendiag || ni < 2) {
            sc[mf][ni] =
                __builtin_amdgcn_mfma_f32_16x16x32_bf16(qf[mf][0], cK[ni][0], sc[mf][ni], 0, 0, 0);
            sc[mf][ni] =
                __builtin_amdgcn_mfma_f32_16x16x32_bf16(qf[mf][1], cK[ni][1], sc[mf][ni], 0, 0, 0);
          }
        }
      __builtin_amdgcn_s_setprio(0);
      // prefetch next K tile
      if (kt + 1 < kt_end) loadK(nK, (kt + 1) * 64);
      // V for THIS step (L2 latency hides under softmax)
      short8 vCur[4][2];
#pragma unroll
      for (int di = 0; di < 4; ++di) {
        const __hip_bfloat16* vp =
            vt + (vbase + (size_t)(di * 16 + llo) * T_DIM + kt * 64 + lhi * 8);
        vCur[di][0] = *reinterpret_cast<const short8*>(vp);
        vCur[di][1] = *reinterpret_cast<const short8*>(vp + 32);
      }
      // online softmax
      float corr[2][4];
#pragma unroll
      for (int mf = 0; mf < 2; ++mf)
#pragma unroll
        for (int j = 0; j < 4; ++j) {
          const int ql = mf * 16 + lhi * 4 + j;
          float sv[4];
#pragma unroll
          for (int ni = 0; ni < 4; ++ni) {
            float sval = sc[mf][ni][j];
            if (diag) sval = (ni * 16 + llo <= base + ql) ? sval : -1e30f;
            sv[ni] = sval;
          }
          float mx = fmaxf(fmaxf(sv[0], sv[1]), fmaxf(sv[2], sv[3]));
#pragma unroll
          for (int d = 1; d < 16; d <<= 1) mx = fmaxf(mx, __shfl_xor(mx, d));
          const float mnew = fmaxf(mrun[mf][j], mx);
          const float c = __expf(mrun[mf][j] - mnew);
          mrun[mf][j] = mnew;
          corr[mf][j] = c;
#pragma unroll
          for (int ni = 0; ni < 4; ++ni)
            sP[w][mf * 16 + lhi * 4 + j][ni * 16 + llo] = __float2bfloat16(__expf(sv[ni] - mnew));
#pragma unroll
          for (int di = 0; di < 4; ++di) oacc[mf][di][j] *= c;
        }
      asm volatile("s_waitcnt lgkmcnt(0)" ::: "memory");
      // O += P V ; l += P 1
      __builtin_amdgcn_s_setprio(1);
#pragma unroll
      for (int mf = 0; mf < 2; ++mf) {
        const short8 pf0 = *reinterpret_cast<const short8*>(&sP[w][mf * 16 + llo][lhi * 8]);
        const short8 pf1 = *reinterpret_cast<const short8*>(&sP[w][mf * 16 + llo][32 + lhi * 8]);
        f32x4 lacc = zero4();
        lacc = __builtin_amdgcn_mfma_f32_16x16x32_bf16(pf0, onesb, lacc, 0, 0, 0);
        if (!evendiag)
          lacc = __builtin_amdgcn_mfma_f32_16x16x32_bf16(pf1, onesb, lacc, 0, 0, 0);
#pragma unroll
        for (int di = 0; di < 4; ++di) {
          oacc[mf][di] =
              __builtin_amdgcn_mfma_f32_16x16x32_bf16(pf0, vCur[di][0], oacc[mf][di], 0, 0, 0);
          if (!evendiag)
            oacc[mf][di] =
                __builtin_amdgcn_mfma_f32_16x16x32_bf16(pf1, vCur[di][1], oacc[mf][di], 0, 0, 0);
        }
#pragma unroll
        for (int j = 0; j < 4; ++j)
          lrun[mf][j] = lrun[mf][j] * corr[mf][j] + lacc[j];
      }
      __builtin_amdgcn_s_setprio(0);
    };

    short8 kA[4][2], kB[4][2];
    if (kt_begin < kt_end) loadK(kA, kt_begin * 64);
    for (int kt = kt_begin; kt < kt_end; ++kt) {
      if ((kt - kt_begin) & 1) step(kB, kA, kt);
      else                     step(kA, kB, kt);
    }

    // ---- merge the two kv-halves (flash-decoding combine) ----
    if (s == 0) {
      float* dst = &mrg[pr][l][0];
#pragma unroll
      for (int mf = 0; mf < 2; ++mf)
#pragma unroll
        for (int di = 0; di < 4; ++di)
#pragma unroll
          for (int j = 0; j < 4; ++j) dst[(mf * 4 + di) * 4 + j] = oacc[mf][di][j];
#pragma unroll
      for (int mf = 0; mf < 2; ++mf)
#pragma unroll
        for (int j = 0; j < 4; ++j) {
          dst[32 + mf * 4 + j] = mrun[mf][j];
          dst[40 + mf * 4 + j] = lrun[mf][j];
        }
    }
    __syncthreads();
    if (s == 1) {
      const float* src = &mrg[pr][l][0];
#pragma unroll
      for (int mf = 0; mf < 2; ++mf)
#pragma unroll
        for (int j = 0; j < 4; ++j) {
          const float m0 = src[32 + mf * 4 + j], l0 = src[40 + mf * 4 + j];
          const float m1 = mrun[mf][j], l1 = lrun[mf][j];
          const float mm = fmaxf(m0, m1);
          const float a0 = __expf(m0 - mm), a1 = __expf(m1 - mm);
          const float linv = 1.0f / (l0 * a0 + l1 * a1);
          const size_t row = rb + q0 + mf * 16 + lhi * 4 + j;
#pragma unroll
          for (int di = 0; di < 4; ++di) {
            const float o = (src[(mf * 4 + di) * 4 + j] * a0 + oacc[mf][di][j] * a1) * linv;
            aout[row * 1024 + h * 64 + di * 16 + llo] = __float2bfloat16(o);
          }
        }
    }
    __syncthreads();
  }
}

// ---------------- launch ----------------
extern "C" void kernel_launch(void* const* d_in, const int* in_sizes, int n_in,
                              void* d_out, int out_size, void* d_ws, size_t ws_size,
                              hipStream_t stream) {
  (void)in_sizes; (void)n_in; (void)out_size; (void)ws_size;
  const float* x      = (const float*)d_in[0];
  const float* ln1_g  = (const float*)d_in[1];
  const float* ln1_b  = (const float*)d_in[2];
  const float* w_qkv  = (const float*)d_in[3];
  const float* b_qkv  = (const float*)d_in[4];
  const float* w_out  = (const float*)d_in[5];
  const float* b_out  = (const float*)d_in[6];
  const float* ln2_g  = (const float*)d_in[7];
  const float* ln2_b  = (const float*)d_in[8];
  const float* w_fc   = (const float*)d_in[9];
  const float* b_fc   = (const float*)d_in[10];
  const float* w_proj = (const float*)d_in[11];
  const float* b_proj = (const float*)d_in[12];
  float* out = (float*)d_out;

  const int M = 2 * T_DIM;  // 4096 rows
  char* wsp = (char*)d_ws;
  size_t off = 0;
  auto carve = [&](size_t bytes) {
    void* p = wsp + off;
    off += (bytes + 255) & ~(size_t)255;
    return p;
  };
  __hip_bfloat16* wt_qkv  = (__hip_bfloat16*)carve((size_t)3072 * 1024 * 2);
  __hip_bfloat16* wt_out  = (__hip_bfloat16*)carve((size_t)1024 * 1024 * 2);
  __hip_bfloat16* wt_fc   = (__hip_bfloat16*)carve((size_t)4096 * 1024 * 2);
  __hip_bfloat16* wt_proj = (__hip_bfloat16*)carve((size_t)1024 * 4096 * 2);
  __hip_bfloat16* ln1o    = (__hip_bfloat16*)carve((size_t)M * 1024 * 2);
  __hip_bfloat16* qkvb    = (__hip_bfloat16*)carve((size_t)M * 3072 * 2);
  __hip_bfloat16* vtb     = (__hip_bfloat16*)carve((size_t)2 * NH * 64 * T_DIM * 2);
  __hip_bfloat16* attnb   = (__hip_bfloat16*)carve((size_t)M * 1024 * 2);
  float*          x2      = (float*)carve((size_t)M * 1024 * 4);
  __hip_bfloat16* h1      = (__hip_bfloat16*)carve((size_t)M * 4096 * 2);
  __hip_bfloat16* ln2o    = ln1o;  // ln1 output dead after QKV GEMM; reuse

  // fused prologue: 4 weight transposes + LN1 in one launch
  prep<<<4096, 256, 0, stream>>>(w_qkv, w_out, w_fc, w_proj,
                                 wt_qkv, wt_out, wt_fc, wt_proj,
                                 x, ln1_g, ln1_b, ln1o);
  gemm_bt<0, 0, 0, 1><<<dim3(3072 / 128, M / 128), 256, 0, stream>>>(
      ln1o, wt_qkv, b_qkv, nullptr, nullptr, qkvb, M, 3072, 1024);
  transpose_v<<<dim3(T_DIM / 64, NH, 2), 256, 0, stream>>>(qkvb, vtb);
  attn_fwd<<<dim3(32, 16), 256, 0, stream>>>(qkvb, vtb, attnb);
  gemm_small<1, 1><<<dim3(1024 / 128, M / 64), 256, 0, stream>>>(
      attnb, wt_out, b_out, x, x2, nullptr, M, 1024, 1024);
  layernorm_bf16<<<M / 4, 256, 0, stream>>>(x2, ln2_g, ln2_b, ln2o);
  gemm_bt<1, 0, 0, 0><<<dim3(4096 / 128, M / 128), 256, 0, stream>>>(
      ln2o, wt_fc, b_fc, nullptr, nullptr, h1, M, 4096, 1024);
  gemm_small<1, 1><<<dim3(1024 / 128, M / 64), 256, 0, stream>>>(
      h1, wt_proj, b_proj, x2, out, nullptr, M, 1024, 4096);
}